// Round 1
// baseline (1234.216 us; speedup 1.0000x reference)
//
#include <hip/hip_runtime.h>
#include <math.h>

#define HC 256
#define NH 8
#define NOUT 10
#define NGRAPH 64

__device__ __forceinline__ float lrelu(float v) { return v > 0.f ? v : 0.2f * v; }

// ---------------- CSR build ----------------
__global__ void k_zero_i32(int* p, int n) {
  int i = blockIdx.x * blockDim.x + threadIdx.x;
  if (i < n) p[i] = 0;
}

__global__ void k_deg(const int* __restrict__ dst, int E, int* __restrict__ deg) {
  int e = blockIdx.x * blockDim.x + threadIdx.x;
  if (e < E) atomicAdd(&deg[dst[e]], 1);
}

__global__ void k_scan(const int* __restrict__ deg, int* __restrict__ ptr,
                       int* __restrict__ cur, int n) {
  __shared__ int part[1024];
  __shared__ int pexc[1025];
  int t = threadIdx.x;
  int chunk = (n + 1023) / 1024;
  int lo = t * chunk, hi = lo + chunk;
  if (lo > n) lo = n;
  if (hi > n) hi = n;
  int s = 0;
  for (int i = lo; i < hi; ++i) s += deg[i];
  part[t] = s;
  __syncthreads();
  if (t == 0) {
    int run = 0;
    for (int i = 0; i < 1024; ++i) { pexc[i] = run; run += part[i]; }
    pexc[1024] = run;
  }
  __syncthreads();
  int run = pexc[t];
  for (int i = lo; i < hi; ++i) { ptr[i] = run; cur[i] = run; run += deg[i]; }
  if (t == 0) ptr[n] = pexc[1024];
}

__global__ void k_scatter(const int* __restrict__ src, const int* __restrict__ dst, int E,
                          int* __restrict__ cur, int* __restrict__ csrc) {
  int e = blockIdx.x * blockDim.x + threadIdx.x;
  if (e < E) {
    int pos = atomicAdd(&cur[dst[e]], 1);
    csrc[pos] = src[e];
  }
}

// ---------------- SGEMM: h[N,256] = x[N,K] @ W[K,256] ----------------
// 64 rows x 256 cols per block, 8x8 per thread, K-tile 32.
__global__ __launch_bounds__(256) void k_gemm(const float* __restrict__ x,
                                              const float* __restrict__ w,
                                              float* __restrict__ h, int Nn, int K) {
  __shared__ float Xt[32][65];   // [kk][row], padded
  __shared__ float Wt[32][257];  // [kk][col], padded
  int t = threadIdx.x;
  int r0 = blockIdx.x * 64;
  int rg = t >> 5, cl = t & 31;
  float acc[8][8];
#pragma unroll
  for (int i = 0; i < 8; ++i)
#pragma unroll
    for (int j = 0; j < 8; ++j) acc[i][j] = 0.f;

  for (int k0 = 0; k0 < K; k0 += 32) {
#pragma unroll
    for (int i = 0; i < 8; ++i) {
      int idx = i * 256 + t;
      int r = idx >> 5, kk = idx & 31;
      int row = r0 + r;
      Xt[kk][r] = (row < Nn) ? x[(long)row * K + k0 + kk] : 0.f;
    }
#pragma unroll
    for (int i = 0; i < 32; ++i) Wt[i][t] = w[(long)(k0 + i) * HC + t];
    __syncthreads();
#pragma unroll
    for (int kk = 0; kk < 32; ++kk) {
      float xr[8], wc[8];
#pragma unroll
      for (int i = 0; i < 8; ++i) xr[i] = Xt[kk][rg * 8 + i];
#pragma unroll
      for (int j = 0; j < 8; ++j) wc[j] = Wt[kk][j * 32 + cl];
#pragma unroll
      for (int i = 0; i < 8; ++i)
#pragma unroll
        for (int j = 0; j < 8; ++j) acc[i][j] += xr[i] * wc[j];
    }
    __syncthreads();
  }
#pragma unroll
  for (int i = 0; i < 8; ++i) {
    int row = r0 + rg * 8 + i;
    if (row < Nn) {
#pragma unroll
      for (int j = 0; j < 8; ++j) h[(long)row * HC + j * 32 + cl] = acc[i][j];
    }
  }
}

// ---------------- per-node attention scores s,d ----------------
__global__ __launch_bounds__(256) void k_sd(const float* __restrict__ h,
                                            const float* __restrict__ as,
                                            const float* __restrict__ ad,
                                            float* __restrict__ s, float* __restrict__ d, int Nn) {
  int wid = (blockIdx.x * blockDim.x + threadIdx.x) >> 6;
  int lane = threadIdx.x & 63;
  if (wid >= Nn) return;
  float4 hv = ((const float4*)(h + (long)wid * HC))[lane];
  float4 av = ((const float4*)as)[lane];
  float4 bv = ((const float4*)ad)[lane];
  float ssum = hv.x * av.x + hv.y * av.y + hv.z * av.z + hv.w * av.w;
  float dsum = hv.x * bv.x + hv.y * bv.y + hv.z * bv.z + hv.w * bv.w;
#pragma unroll
  for (int m = 1; m <= 4; m <<= 1) {
    ssum += __shfl_xor(ssum, m, 64);
    dsum += __shfl_xor(dsum, m, 64);
  }
  if ((lane & 7) == 0) {
    int hd = lane >> 3;
    s[wid * NH + hd] = ssum;
    d[wid * NH + hd] = dsum;
  }
}

// ---------------- fused attention aggregation (one wave per dst node) ----------------
// lane owns flat channels [4*lane, 4*lane+4) -> head = lane>>3
__global__ __launch_bounds__(256) void k_aggr(const float* __restrict__ h,
                                              const float* __restrict__ s,
                                              const float* __restrict__ dsc,
                                              const int* __restrict__ ptr,
                                              const int* __restrict__ csrc,
                                              const float* __restrict__ bias,
                                              float* __restrict__ xout, int Nn) {
  int wid = (blockIdx.x * blockDim.x + threadIdx.x) >> 6;
  int lane = threadIdx.x & 63;
  if (wid >= Nn) return;
  int n = wid;
  int hd = lane >> 3;
  int e0 = ptr[n], e1 = ptr[n + 1];
  float dn = dsc[n * NH + hd];
  float eself = lrelu(s[n * NH + hd] + dn);

  // phase 1: per-head max (8 edges/iter across lanes; lane&7 = edge slot)
  float m = eself;
  for (int e = e0 + (lane & 7); e < e1; e += 8) {
    int src = csrc[e];
    m = fmaxf(m, lrelu(s[src * NH + hd] + dn));
  }
  m = fmaxf(m, __shfl_xor(m, 1, 64));
  m = fmaxf(m, __shfl_xor(m, 2, 64));
  m = fmaxf(m, __shfl_xor(m, 4, 64));

  // phase 2: denom + unnormalized message accumulation
  float p = __expf(eself - m);
  float denom = p;
  float4 hv = ((const float4*)(h + (long)n * HC))[lane];
  float ax = p * hv.x, ay = p * hv.y, az = p * hv.z, aw = p * hv.w;
  for (int e = e0; e < e1; ++e) {
    int src = csrc[e];
    float ex = __expf(lrelu(s[src * NH + hd] + dn) - m);
    denom += ex;
    float4 hs = ((const float4*)(h + (long)src * HC))[lane];
    ax += ex * hs.x; ay += ex * hs.y; az += ex * hs.z; aw += ex * hs.w;
  }

  float inv = 1.f / (denom + 1e-16f);
  float4 bv = ((const float4*)bias)[lane];
  float ox = ax * inv + bv.x;
  float oy = ay * inv + bv.y;
  float oz = az * inv + bv.z;
  float ow = aw * inv + bv.w;
  ox = ox > 0.f ? ox : __expf(ox) - 1.f;
  oy = oy > 0.f ? oy : __expf(oy) - 1.f;
  oz = oz > 0.f ? oz : __expf(oz) - 1.f;
  ow = ow > 0.f ? ow : __expf(ow) - 1.f;
  ((float4*)(xout + (long)n * HC))[lane] = make_float4(ox, oy, oz, ow);
}

// ---------------- mean pool + linear ----------------
__global__ __launch_bounds__(256) void k_pool(const float* __restrict__ x,
                                              const int* __restrict__ batch,
                                              const float* __restrict__ lw,
                                              const float* __restrict__ lb,
                                              float* __restrict__ out, int Nn) {
  __shared__ float pooled[HC];
  int g = blockIdx.x;
  int t = threadIdx.x;
  int a = 0, b = Nn;
  while (a < b) { int mid = (a + b) >> 1; if (batch[mid] < g) a = mid + 1; else b = mid; }
  int lo = a;
  b = Nn;
  while (a < b) { int mid = (a + b) >> 1; if (batch[mid] < g + 1) a = mid + 1; else b = mid; }
  int hi = a;
  float sum = 0.f;
  for (int nidx = lo; nidx < hi; ++nidx) sum += x[(long)nidx * HC + t];
  int cnt = hi - lo;
  pooled[t] = sum / (float)(cnt > 0 ? cnt : 1);
  __syncthreads();
  if (t < NOUT) {
    float acc = lb[t];
    for (int c = 0; c < HC; ++c) acc += pooled[c] * lw[c * NOUT + t];
    out[g * NOUT + t] = acc;
  }
}

extern "C" void kernel_launch(void* const* d_in, const int* in_sizes, int n_in,
                              void* d_out, int out_size, void* d_ws, size_t ws_size,
                              hipStream_t stream) {
  const float* x_in = (const float*)d_in[0];
  const int* ei     = (const int*)d_in[1];
  const int* batch  = (const int*)d_in[2];
  const float* w1 = (const float*)d_in[3];
  const float* as1 = (const float*)d_in[4];
  const float* ad1 = (const float*)d_in[5];
  const float* b1 = (const float*)d_in[6];
  const float* w2 = (const float*)d_in[7];
  const float* as2 = (const float*)d_in[8];
  const float* ad2 = (const float*)d_in[9];
  const float* b2 = (const float*)d_in[10];
  const float* w3 = (const float*)d_in[11];
  const float* as3 = (const float*)d_in[12];
  const float* ad3 = (const float*)d_in[13];
  const float* b3 = (const float*)d_in[14];
  const float* lw = (const float*)d_in[15];
  const float* lb = (const float*)d_in[16];

  int Nn = in_sizes[2];
  int E = in_sizes[1] / 2;
  const int* esrc = ei;
  const int* edst = ei + E;

  char* ws = (char*)d_ws;
  size_t off = 0;
  auto alloc = [&](size_t bytes) {
    char* p = ws + off;
    off += (bytes + 255) & ~(size_t)255;
    return p;
  };
  float* xbuf = (float*)alloc((size_t)Nn * HC * 4);
  float* hbuf = (float*)alloc((size_t)Nn * HC * 4);
  float* sbuf = (float*)alloc((size_t)Nn * NH * 4);
  float* dbuf = (float*)alloc((size_t)Nn * NH * 4);
  int* deg  = (int*)alloc((size_t)(Nn + 1) * 4);
  int* ptr  = (int*)alloc((size_t)(Nn + 1) * 4);
  int* cur  = (int*)alloc((size_t)Nn * 4);
  int* csrc = (int*)alloc((size_t)E * 4);

  // CSR by dst (deterministic work; intra-segment order atomic-raced, FP-noise only)
  k_zero_i32<<<(Nn + 255) / 256, 256, 0, stream>>>(deg, Nn);
  k_deg<<<(E + 255) / 256, 256, 0, stream>>>(edst, E, deg);
  k_scan<<<1, 1024, 0, stream>>>(deg, ptr, cur, Nn);
  k_scatter<<<(E + 255) / 256, 256, 0, stream>>>(esrc, edst, E, cur, csrc);

  const float* Ws[3] = {w1, w2, w3};
  const float* As[3] = {as1, as2, as3};
  const float* Ad[3] = {ad1, ad2, ad3};
  const float* Bs[3] = {b1, b2, b3};

  const float* cx = x_in;
  int K = in_sizes[0] / Nn;  // 128 for layer 1
  int gemmGrid = (Nn + 63) / 64;
  int waveGrid = ((Nn * 64) + 255) / 256;
  for (int l = 0; l < 3; ++l) {
    k_gemm<<<gemmGrid, 256, 0, stream>>>(cx, Ws[l], hbuf, Nn, K);
    k_sd<<<waveGrid, 256, 0, stream>>>(hbuf, As[l], Ad[l], sbuf, dbuf, Nn);
    k_aggr<<<waveGrid, 256, 0, stream>>>(hbuf, sbuf, dbuf, ptr, csrc, Bs[l], xbuf, Nn);
    cx = xbuf;
    K = HC;
  }
  k_pool<<<NGRAPH, 256, 0, stream>>>(xbuf, batch, lw, lb, (float*)d_out, Nn);
}

// Round 2
// 878.502 us; speedup vs baseline: 1.4049x; 1.4049x over previous
//
#include <hip/hip_runtime.h>
#include <hip/hip_bf16.h>
#include <math.h>

#define HC 256
#define NH 8
#define NOUT 10
#define NGRAPH 64

__device__ __forceinline__ float lrelu(float v) { return v > 0.f ? v : 0.2f * v; }

__device__ __forceinline__ void unp4(uint2 v, float& a, float& b, float& c, float& d) {
  a = __uint_as_float(v.x << 16);
  b = __uint_as_float(v.x & 0xffff0000u);
  c = __uint_as_float(v.y << 16);
  d = __uint_as_float(v.y & 0xffff0000u);
}

// ---------------- CSR build ----------------
__global__ void k_zero_i32(int* p, int n) {
  int i = blockIdx.x * blockDim.x + threadIdx.x;
  if (i < n) p[i] = 0;
}
__global__ void k_zero_f32(float* p, int n) {
  int i = blockIdx.x * blockDim.x + threadIdx.x;
  if (i < n) p[i] = 0.f;
}

__global__ void k_deg(const int* __restrict__ dst, int E, int* __restrict__ deg) {
  int e = blockIdx.x * blockDim.x + threadIdx.x;
  if (e < E) atomicAdd(&deg[dst[e]], 1);
}

__global__ void k_scan(const int* __restrict__ deg, int* __restrict__ ptr,
                       int* __restrict__ cur, int n) {
  __shared__ int part[1024];
  __shared__ int pexc[1025];
  int t = threadIdx.x;
  int chunk = (n + 1023) / 1024;
  int lo = t * chunk, hi = lo + chunk;
  if (lo > n) lo = n;
  if (hi > n) hi = n;
  int s = 0;
  for (int i = lo; i < hi; ++i) s += deg[i];
  part[t] = s;
  __syncthreads();
  if (t == 0) {
    int run = 0;
    for (int i = 0; i < 1024; ++i) { pexc[i] = run; run += part[i]; }
    pexc[1024] = run;
  }
  __syncthreads();
  int run = pexc[t];
  for (int i = lo; i < hi; ++i) { ptr[i] = run; cur[i] = run; run += deg[i]; }
  if (t == 0) ptr[n] = pexc[1024];
}

__global__ void k_scatter(const int* __restrict__ src, const int* __restrict__ dst, int E,
                          int* __restrict__ cur, int* __restrict__ csrc) {
  int e = blockIdx.x * blockDim.x + threadIdx.x;
  if (e < E) {
    int pos = atomicAdd(&cur[dst[e]], 1);
    csrc[pos] = src[e];
  }
}

// ---------------- SGEMM: h[N,256] = x[N,K] @ W[K,256], bf16 output ----------------
__global__ __launch_bounds__(256) void k_gemm(const float* __restrict__ x,
                                              const float* __restrict__ w,
                                              __hip_bfloat16* __restrict__ h, int Nn, int K) {
  __shared__ float Xt[32][65];   // [kk][row], padded
  __shared__ float Wt[32][257];  // [kk][col], padded
  int t = threadIdx.x;
  int r0 = blockIdx.x * 64;
  int rg = t >> 5, cl = t & 31;
  float acc[8][8];
#pragma unroll
  for (int i = 0; i < 8; ++i)
#pragma unroll
    for (int j = 0; j < 8; ++j) acc[i][j] = 0.f;

  for (int k0 = 0; k0 < K; k0 += 32) {
#pragma unroll
    for (int i = 0; i < 8; ++i) {
      int idx = i * 256 + t;
      int r = idx >> 5, kk = idx & 31;
      int row = r0 + r;
      Xt[kk][r] = (row < Nn) ? x[(long)row * K + k0 + kk] : 0.f;
    }
#pragma unroll
    for (int i = 0; i < 32; ++i) Wt[i][t] = w[(long)(k0 + i) * HC + t];
    __syncthreads();
#pragma unroll
    for (int kk = 0; kk < 32; ++kk) {
      float xr[8], wc[8];
#pragma unroll
      for (int i = 0; i < 8; ++i) xr[i] = Xt[kk][rg * 8 + i];
#pragma unroll
      for (int j = 0; j < 8; ++j) wc[j] = Wt[kk][j * 32 + cl];
#pragma unroll
      for (int i = 0; i < 8; ++i)
#pragma unroll
        for (int j = 0; j < 8; ++j) acc[i][j] += xr[i] * wc[j];
    }
    __syncthreads();
  }
#pragma unroll
  for (int i = 0; i < 8; ++i) {
    int row = r0 + rg * 8 + i;
    if (row < Nn) {
#pragma unroll
      for (int j = 0; j < 8; ++j)
        h[(long)row * HC + j * 32 + cl] = __float2bfloat16(acc[i][j]);
    }
  }
}

// ---------------- per-node attention scores s,d (reads bf16 h) ----------------
__global__ __launch_bounds__(256) void k_sd(const ushort* __restrict__ h,
                                            const float* __restrict__ as,
                                            const float* __restrict__ ad,
                                            float* __restrict__ s, float* __restrict__ d, int Nn) {
  int wid = (blockIdx.x * blockDim.x + threadIdx.x) >> 6;
  int lane = threadIdx.x & 63;
  if (wid >= Nn) return;
  uint2 hv = ((const uint2*)(h + (size_t)wid * HC))[lane];
  float h0, h1, h2, h3;
  unp4(hv, h0, h1, h2, h3);
  float4 av = ((const float4*)as)[lane];
  float4 bv = ((const float4*)ad)[lane];
  float ssum = h0 * av.x + h1 * av.y + h2 * av.z + h3 * av.w;
  float dsum = h0 * bv.x + h1 * bv.y + h2 * bv.z + h3 * bv.w;
#pragma unroll
  for (int m = 1; m <= 4; m <<= 1) {
    ssum += __shfl_xor(ssum, m, 64);
    dsum += __shfl_xor(dsum, m, 64);
  }
  if ((lane & 7) == 0) {
    int hd = lane >> 3;
    s[wid * NH + hd] = ssum;
    d[wid * NH + hd] = dsum;
  }
}

// ---------------- fused attention aggregation (one wave per dst node, bf16 gathers) ----------------
__global__ __launch_bounds__(256) void k_aggr(const ushort* __restrict__ h,
                                              const float* __restrict__ s,
                                              const float* __restrict__ dsc,
                                              const int* __restrict__ ptr,
                                              const int* __restrict__ csrc,
                                              const float* __restrict__ bias,
                                              float* __restrict__ xout, int Nn) {
  int wid = (blockIdx.x * blockDim.x + threadIdx.x) >> 6;
  int lane = threadIdx.x & 63;
  if (wid >= Nn) return;
  int n = wid;
  int hd = lane >> 3;
  int e0 = ptr[n], e1 = ptr[n + 1];
  float dn = dsc[n * NH + hd];
  float eself = lrelu(s[n * NH + hd] + dn);

  // phase 1: per-head max (8 edges/iter across lanes; lane&7 = edge slot)
  float m = eself;
  for (int e = e0 + (lane & 7); e < e1; e += 8) {
    int src = csrc[e];
    m = fmaxf(m, lrelu(s[src * NH + hd] + dn));
  }
  m = fmaxf(m, __shfl_xor(m, 1, 64));
  m = fmaxf(m, __shfl_xor(m, 2, 64));
  m = fmaxf(m, __shfl_xor(m, 4, 64));

  // phase 2: denom + unnormalized message accumulation (unroll 2, dual acc)
  float p = __expf(eself - m);
  float denom = p;
  float h0, h1, h2, h3;
  unp4(((const uint2*)(h + (size_t)n * HC))[lane], h0, h1, h2, h3);
  float ax = p * h0, ay = p * h1, az = p * h2, aw = p * h3;
  float bx = 0.f, by = 0.f, bz = 0.f, bw = 0.f;
  int e = e0;
  for (; e + 2 <= e1; e += 2) {
    int sa = csrc[e];
    int sb = csrc[e + 1];
    float ea = __expf(lrelu(s[sa * NH + hd] + dn) - m);
    float eb = __expf(lrelu(s[sb * NH + hd] + dn) - m);
    uint2 va = ((const uint2*)(h + (size_t)sa * HC))[lane];
    uint2 vb = ((const uint2*)(h + (size_t)sb * HC))[lane];
    denom += ea + eb;
    float a0, a1, a2, a3, c0, c1, c2, c3;
    unp4(va, a0, a1, a2, a3);
    unp4(vb, c0, c1, c2, c3);
    ax += ea * a0; ay += ea * a1; az += ea * a2; aw += ea * a3;
    bx += eb * c0; by += eb * c1; bz += eb * c2; bw += eb * c3;
  }
  if (e < e1) {
    int sa = csrc[e];
    float ea = __expf(lrelu(s[sa * NH + hd] + dn) - m);
    denom += ea;
    uint2 va = ((const uint2*)(h + (size_t)sa * HC))[lane];
    float a0, a1, a2, a3;
    unp4(va, a0, a1, a2, a3);
    ax += ea * a0; ay += ea * a1; az += ea * a2; aw += ea * a3;
  }
  ax += bx; ay += by; az += bz; aw += bw;

  float inv = 1.f / (denom + 1e-16f);
  float4 bv = ((const float4*)bias)[lane];
  float ox = ax * inv + bv.x;
  float oy = ay * inv + bv.y;
  float oz = az * inv + bv.z;
  float ow = aw * inv + bv.w;
  ox = ox > 0.f ? ox : __expf(ox) - 1.f;
  oy = oy > 0.f ? oy : __expf(oy) - 1.f;
  oz = oz > 0.f ? oz : __expf(oz) - 1.f;
  ow = ow > 0.f ? ow : __expf(ow) - 1.f;
  ((float4*)(xout + (long)n * HC))[lane] = make_float4(ox, oy, oz, ow);
}

// ---------------- mean pool stage 1: segmented partial sums ----------------
__global__ __launch_bounds__(256) void k_pool1(const float* __restrict__ x,
                                               const int* __restrict__ batch,
                                               float* __restrict__ sums, int Nn) {
  __shared__ int bg[64];
  int n0 = blockIdx.x * 64;
  if (n0 >= Nn) return;
  int t = threadIdx.x;
  int n1 = n0 + 64;
  if (n1 > Nn) n1 = Nn;
  if (t < 64 && n0 + t < Nn) bg[t] = batch[n0 + t];
  __syncthreads();
  float acc = 0.f;
  int gcur = bg[0];
  for (int n = n0; n < n1; ++n) {
    int g = bg[n - n0];
    if (g != gcur) {
      atomicAdd(&sums[gcur * HC + t], acc);
      acc = 0.f;
      gcur = g;
    }
    acc += x[(long)n * HC + t];
  }
  atomicAdd(&sums[gcur * HC + t], acc);
}

// ---------------- pool finalize: divide by count + linear ----------------
__global__ __launch_bounds__(256) void k_pool2(const float* __restrict__ sums,
                                               const int* __restrict__ batch,
                                               const float* __restrict__ lw,
                                               const float* __restrict__ lb,
                                               float* __restrict__ out, int Nn) {
  __shared__ float pooled[HC];
  int g = blockIdx.x;
  int t = threadIdx.x;
  int a = 0, b = Nn;
  while (a < b) { int mid = (a + b) >> 1; if (batch[mid] < g) a = mid + 1; else b = mid; }
  int lo = a;
  b = Nn;
  while (a < b) { int mid = (a + b) >> 1; if (batch[mid] < g + 1) a = mid + 1; else b = mid; }
  int hi = a;
  int cnt = hi - lo;
  pooled[t] = sums[g * HC + t] / (float)(cnt > 0 ? cnt : 1);
  __syncthreads();
  if (t < NOUT) {
    float acc = lb[t];
    for (int c = 0; c < HC; ++c) acc += pooled[c] * lw[c * NOUT + t];
    out[g * NOUT + t] = acc;
  }
}

extern "C" void kernel_launch(void* const* d_in, const int* in_sizes, int n_in,
                              void* d_out, int out_size, void* d_ws, size_t ws_size,
                              hipStream_t stream) {
  const float* x_in = (const float*)d_in[0];
  const int* ei     = (const int*)d_in[1];
  const int* batch  = (const int*)d_in[2];
  const float* w1 = (const float*)d_in[3];
  const float* as1 = (const float*)d_in[4];
  const float* ad1 = (const float*)d_in[5];
  const float* b1 = (const float*)d_in[6];
  const float* w2 = (const float*)d_in[7];
  const float* as2 = (const float*)d_in[8];
  const float* ad2 = (const float*)d_in[9];
  const float* b2 = (const float*)d_in[10];
  const float* w3 = (const float*)d_in[11];
  const float* as3 = (const float*)d_in[12];
  const float* ad3 = (const float*)d_in[13];
  const float* b3 = (const float*)d_in[14];
  const float* lw = (const float*)d_in[15];
  const float* lb = (const float*)d_in[16];

  int Nn = in_sizes[2];
  int E = in_sizes[1] / 2;
  const int* esrc = ei;
  const int* edst = ei + E;

  char* ws = (char*)d_ws;
  size_t off = 0;
  auto alloc = [&](size_t bytes) {
    char* p = ws + off;
    off += (bytes + 255) & ~(size_t)255;
    return p;
  };
  float* xbuf = (float*)alloc((size_t)Nn * HC * 4);
  __hip_bfloat16* hbuf = (__hip_bfloat16*)alloc((size_t)Nn * HC * 2);
  float* sbuf = (float*)alloc((size_t)Nn * NH * 4);
  float* dbuf = (float*)alloc((size_t)Nn * NH * 4);
  float* gsum = (float*)alloc((size_t)NGRAPH * HC * 4);
  int* deg  = (int*)alloc((size_t)(Nn + 1) * 4);
  int* ptr  = (int*)alloc((size_t)(Nn + 1) * 4);
  int* cur  = (int*)alloc((size_t)Nn * 4);
  int* csrc = (int*)alloc((size_t)E * 4);

  // CSR by dst
  k_zero_i32<<<(Nn + 255) / 256, 256, 0, stream>>>(deg, Nn);
  k_deg<<<(E + 255) / 256, 256, 0, stream>>>(edst, E, deg);
  k_scan<<<1, 1024, 0, stream>>>(deg, ptr, cur, Nn);
  k_scatter<<<(E + 255) / 256, 256, 0, stream>>>(esrc, edst, E, cur, csrc);

  const float* Ws[3] = {w1, w2, w3};
  const float* As[3] = {as1, as2, as3};
  const float* Ad[3] = {ad1, ad2, ad3};
  const float* Bs[3] = {b1, b2, b3};

  const float* cx = x_in;
  int K = in_sizes[0] / Nn;  // 128 for layer 1
  int gemmGrid = (Nn + 63) / 64;
  int waveGrid = ((Nn * 64) + 255) / 256;
  for (int l = 0; l < 3; ++l) {
    k_gemm<<<gemmGrid, 256, 0, stream>>>(cx, Ws[l], hbuf, Nn, K);
    k_sd<<<waveGrid, 256, 0, stream>>>((const ushort*)hbuf, As[l], Ad[l], sbuf, dbuf, Nn);
    k_aggr<<<waveGrid, 256, 0, stream>>>((const ushort*)hbuf, sbuf, dbuf, ptr, csrc, Bs[l], xbuf, Nn);
    cx = xbuf;
    K = HC;
  }
  k_zero_f32<<<(NGRAPH * HC + 255) / 256, 256, 0, stream>>>(gsum, NGRAPH * HC);
  k_pool1<<<(Nn + 63) / 64, 256, 0, stream>>>(xbuf, batch, gsum, Nn);
  k_pool2<<<NGRAPH, 256, 0, stream>>>(gsum, batch, lw, lb, (float*)d_out, Nn);
}

// Round 3
// 596.751 us; speedup vs baseline: 2.0682x; 1.4721x over previous
//
#include <hip/hip_runtime.h>
#include <hip/hip_bf16.h>
#include <math.h>

#define HC 256
#define NH 8
#define NOUT 10
#define NGRAPH 64

typedef __bf16 bf16x8 __attribute__((ext_vector_type(8)));
typedef float f32x4 __attribute__((ext_vector_type(4)));

__device__ __forceinline__ float lrelu(float v) { return v > 0.f ? v : 0.2f * v; }

__device__ __forceinline__ ushort f2bu(float f) {
  __hip_bfloat16 b = __float2bfloat16(f);
  return __builtin_bit_cast(ushort, b);
}
__device__ __forceinline__ float bf2f(ushort u) {
  return __uint_as_float(((unsigned)u) << 16);
}
__device__ __forceinline__ void unp4(uint2 v, float& a, float& b, float& c, float& d) {
  a = __uint_as_float(v.x << 16);
  b = __uint_as_float(v.x & 0xffff0000u);
  c = __uint_as_float(v.y << 16);
  d = __uint_as_float(v.y & 0xffff0000u);
}

// ---------------- CSR build ----------------
__global__ void k_zero_i32(int* p, int n) {
  int i = blockIdx.x * blockDim.x + threadIdx.x;
  if (i < n) p[i] = 0;
}
__global__ void k_zero_f32(float* p, int n) {
  int i = blockIdx.x * blockDim.x + threadIdx.x;
  if (i < n) p[i] = 0.f;
}

__global__ void k_deg(const int* __restrict__ dst, int E, int* __restrict__ deg) {
  int e = blockIdx.x * blockDim.x + threadIdx.x;
  if (e < E) atomicAdd(&deg[dst[e]], 1);
}

__global__ void k_scan(const int* __restrict__ deg, int* __restrict__ ptr,
                       int* __restrict__ cur, int n) {
  __shared__ int part[1024];
  __shared__ int pexc[1025];
  int t = threadIdx.x;
  int chunk = (n + 1023) / 1024;
  int lo = t * chunk, hi = lo + chunk;
  if (lo > n) lo = n;
  if (hi > n) hi = n;
  int s = 0;
  for (int i = lo; i < hi; ++i) s += deg[i];
  part[t] = s;
  __syncthreads();
  if (t == 0) {
    int run = 0;
    for (int i = 0; i < 1024; ++i) { pexc[i] = run; run += part[i]; }
    pexc[1024] = run;
  }
  __syncthreads();
  int run = pexc[t];
  for (int i = lo; i < hi; ++i) { ptr[i] = run; cur[i] = run; run += deg[i]; }
  if (t == 0) ptr[n] = pexc[1024];
}

__global__ void k_scatter(const int* __restrict__ src, const int* __restrict__ dst, int E,
                          int* __restrict__ cur, int* __restrict__ csrc) {
  int e = blockIdx.x * blockDim.x + threadIdx.x;
  if (e < E) {
    int pos = atomicAdd(&cur[dst[e]], 1);
    csrc[pos] = src[e];
  }
}

// ---------------- fp32 -> bf16 convert (layer-1 input) ----------------
__global__ void k_f2b(const float* __restrict__ in, ushort* __restrict__ out, int n) {
  int i = blockIdx.x * blockDim.x + threadIdx.x;
  int i4 = i * 4;
  if (i4 + 3 < n) {
    float4 v = ((const float4*)in)[i];
    ushort4 o;
    o.x = f2bu(v.x); o.y = f2bu(v.y); o.z = f2bu(v.z); o.w = f2bu(v.w);
    ((ushort4*)out)[i] = o;
  } else {
    for (int j = i4; j < n; ++j) out[j] = f2bu(in[j]);
  }
}

// ---------------- W repack to MFMA B-fragment layout, bf16 ----------------
// out idx = ((ks*16+ct)*64+lane)*8 + i  <=  W[ks*32+(lane>>4)*8+i][ct*16+(lane&15)]
__global__ void k_wpack(const float* __restrict__ w, ushort* __restrict__ wb, int K) {
  int idx = blockIdx.x * blockDim.x + threadIdx.x;
  if (idx >= K * HC) return;
  int i = idx & 7;
  int lane = (idx >> 3) & 63;
  int ct = (idx >> 9) & 15;
  int ks = idx >> 13;
  int k = ks * 32 + (lane >> 4) * 8 + i;
  int col = ct * 16 + (lane & 15);
  wb[idx] = f2bu(w[k * HC + col]);
}

// ---------------- MFMA GEMM: h[N,256] = xb[N,K] @ W[K,256] (all bf16, fp32 acc) ----
// One wave per 16 rows x 256 cols. No LDS, no barriers: A rows read once (no reuse),
// B-frags from packed table (L2-resident).
template <int K>
__global__ __launch_bounds__(256) void k_gemm_mfma(const ushort* __restrict__ xb,
                                                   const ushort* __restrict__ wb,
                                                   ushort* __restrict__ h, int Nn) {
  int wave = (blockIdx.x * blockDim.x + threadIdx.x) >> 6;
  int lane = threadIdx.x & 63;
  int r0 = wave * 16;
  if (r0 >= Nn) return;
  constexpr int NKS = K / 32;
  f32x4 acc[16];
#pragma unroll
  for (int ct = 0; ct < 16; ++ct) acc[ct] = (f32x4){0.f, 0.f, 0.f, 0.f};
  const ushort* arow = xb + (size_t)(r0 + (lane & 15)) * K + (lane >> 4) * 8;
  const ushort* bbase = wb + (size_t)lane * 8;
#pragma unroll
  for (int ks = 0; ks < NKS; ++ks) {
    uint4 araw = *(const uint4*)(arow + ks * 32);
    bf16x8 af = __builtin_bit_cast(bf16x8, araw);
#pragma unroll
    for (int ct = 0; ct < 16; ++ct) {
      uint4 braw = *(const uint4*)(bbase + (size_t)(ks * 16 + ct) * 512);
      bf16x8 bfr = __builtin_bit_cast(bf16x8, braw);
      acc[ct] = __builtin_amdgcn_mfma_f32_16x16x32_bf16(af, bfr, acc[ct], 0, 0, 0);
    }
  }
  // C/D layout: col = ct*16 + (lane&15), row = r0 + (lane>>4)*4 + q
  int colb = lane & 15;
  int rq = r0 + (lane >> 4) * 4;
#pragma unroll
  for (int ct = 0; ct < 16; ++ct) {
#pragma unroll
    for (int q = 0; q < 4; ++q) {
      h[(size_t)(rq + q) * HC + ct * 16 + colb] = f2bu(acc[ct][q]);
    }
  }
}

// ---------------- per-node attention scores s,d (reads bf16 h) ----------------
__global__ __launch_bounds__(256) void k_sd(const ushort* __restrict__ h,
                                            const float* __restrict__ as,
                                            const float* __restrict__ ad,
                                            float* __restrict__ s, float* __restrict__ d, int Nn) {
  int wid = (blockIdx.x * blockDim.x + threadIdx.x) >> 6;
  int lane = threadIdx.x & 63;
  if (wid >= Nn) return;
  uint2 hv = ((const uint2*)(h + (size_t)wid * HC))[lane];
  float h0, h1, h2, h3;
  unp4(hv, h0, h1, h2, h3);
  float4 av = ((const float4*)as)[lane];
  float4 bv = ((const float4*)ad)[lane];
  float ssum = h0 * av.x + h1 * av.y + h2 * av.z + h3 * av.w;
  float dsum = h0 * bv.x + h1 * bv.y + h2 * bv.z + h3 * bv.w;
#pragma unroll
  for (int m = 1; m <= 4; m <<= 1) {
    ssum += __shfl_xor(ssum, m, 64);
    dsum += __shfl_xor(dsum, m, 64);
  }
  if ((lane & 7) == 0) {
    int hd = lane >> 3;
    s[wid * NH + hd] = ssum;
    d[wid * NH + hd] = dsum;
  }
}

// ---------------- fused attention aggregation (one wave per dst node) ----------------
__global__ __launch_bounds__(256) void k_aggr(const ushort* __restrict__ h,
                                              const float* __restrict__ s,
                                              const float* __restrict__ dsc,
                                              const int* __restrict__ ptr,
                                              const int* __restrict__ csrc,
                                              const float* __restrict__ bias,
                                              ushort* __restrict__ xout, int Nn) {
  int wid = (blockIdx.x * blockDim.x + threadIdx.x) >> 6;
  int lane = threadIdx.x & 63;
  if (wid >= Nn) return;
  int n = wid;
  int hd = lane >> 3;
  int e0 = ptr[n], e1 = ptr[n + 1];
  float dn = dsc[n * NH + hd];
  float eself = lrelu(s[n * NH + hd] + dn);

  // phase 1: per-head max
  float m = eself;
  for (int e = e0 + (lane & 7); e < e1; e += 8) {
    int src = csrc[e];
    m = fmaxf(m, lrelu(s[src * NH + hd] + dn));
  }
  m = fmaxf(m, __shfl_xor(m, 1, 64));
  m = fmaxf(m, __shfl_xor(m, 2, 64));
  m = fmaxf(m, __shfl_xor(m, 4, 64));

  // phase 2: denom + unnormalized message accumulation, unroll 4
  float p = __expf(eself - m);
  float denom = p;
  float h0, h1, h2, h3;
  unp4(((const uint2*)(h + (size_t)n * HC))[lane], h0, h1, h2, h3);
  float a0x = p * h0, a0y = p * h1, a0z = p * h2, a0w = p * h3;
  float a1x = 0.f, a1y = 0.f, a1z = 0.f, a1w = 0.f;
  float a2x = 0.f, a2y = 0.f, a2z = 0.f, a2w = 0.f;
  float a3x = 0.f, a3y = 0.f, a3z = 0.f, a3w = 0.f;
  int e = e0;
  for (; e + 4 <= e1; e += 4) {
    int s0 = csrc[e], s1 = csrc[e + 1], s2 = csrc[e + 2], s3 = csrc[e + 3];
    float e0x = __expf(lrelu(s[s0 * NH + hd] + dn) - m);
    float e1x = __expf(lrelu(s[s1 * NH + hd] + dn) - m);
    float e2x = __expf(lrelu(s[s2 * NH + hd] + dn) - m);
    float e3x = __expf(lrelu(s[s3 * NH + hd] + dn) - m);
    uint2 v0 = ((const uint2*)(h + (size_t)s0 * HC))[lane];
    uint2 v1 = ((const uint2*)(h + (size_t)s1 * HC))[lane];
    uint2 v2 = ((const uint2*)(h + (size_t)s2 * HC))[lane];
    uint2 v3 = ((const uint2*)(h + (size_t)s3 * HC))[lane];
    denom += (e0x + e1x) + (e2x + e3x);
    float b0, b1, b2, b3;
    unp4(v0, b0, b1, b2, b3);
    a0x += e0x * b0; a0y += e0x * b1; a0z += e0x * b2; a0w += e0x * b3;
    unp4(v1, b0, b1, b2, b3);
    a1x += e1x * b0; a1y += e1x * b1; a1z += e1x * b2; a1w += e1x * b3;
    unp4(v2, b0, b1, b2, b3);
    a2x += e2x * b0; a2y += e2x * b1; a2z += e2x * b2; a2w += e2x * b3;
    unp4(v3, b0, b1, b2, b3);
    a3x += e3x * b0; a3y += e3x * b1; a3z += e3x * b2; a3w += e3x * b3;
  }
  for (; e < e1; ++e) {
    int sa = csrc[e];
    float ea = __expf(lrelu(s[sa * NH + hd] + dn) - m);
    denom += ea;
    uint2 va = ((const uint2*)(h + (size_t)sa * HC))[lane];
    float b0, b1, b2, b3;
    unp4(va, b0, b1, b2, b3);
    a0x += ea * b0; a0y += ea * b1; a0z += ea * b2; a0w += ea * b3;
  }
  float ax = (a0x + a1x) + (a2x + a3x);
  float ay = (a0y + a1y) + (a2y + a3y);
  float az = (a0z + a1z) + (a2z + a3z);
  float aw = (a0w + a1w) + (a2w + a3w);

  float inv = 1.f / (denom + 1e-16f);
  float4 bv = ((const float4*)bias)[lane];
  float ox = ax * inv + bv.x;
  float oy = ay * inv + bv.y;
  float oz = az * inv + bv.z;
  float ow = aw * inv + bv.w;
  ox = ox > 0.f ? ox : __expf(ox) - 1.f;
  oy = oy > 0.f ? oy : __expf(oy) - 1.f;
  oz = oz > 0.f ? oz : __expf(oz) - 1.f;
  ow = ow > 0.f ? ow : __expf(ow) - 1.f;
  uint2 o;
  o.x = (uint)f2bu(ox) | ((uint)f2bu(oy) << 16);
  o.y = (uint)f2bu(oz) | ((uint)f2bu(ow) << 16);
  ((uint2*)(xout + (size_t)n * HC))[lane] = o;
}

// ---------------- mean pool stage 1: segmented partial sums (bf16 in) ----------------
__global__ __launch_bounds__(256) void k_pool1(const ushort* __restrict__ x,
                                               const int* __restrict__ batch,
                                               float* __restrict__ sums, int Nn) {
  __shared__ int bg[64];
  int n0 = blockIdx.x * 64;
  if (n0 >= Nn) return;
  int t = threadIdx.x;
  int n1 = n0 + 64;
  if (n1 > Nn) n1 = Nn;
  if (t < 64 && n0 + t < Nn) bg[t] = batch[n0 + t];
  __syncthreads();
  float acc = 0.f;
  int gcur = bg[0];
  for (int n = n0; n < n1; ++n) {
    int g = bg[n - n0];
    if (g != gcur) {
      atomicAdd(&sums[gcur * HC + t], acc);
      acc = 0.f;
      gcur = g;
    }
    acc += bf2f(x[(size_t)n * HC + t]);
  }
  atomicAdd(&sums[gcur * HC + t], acc);
}

// ---------------- pool finalize: divide by count + linear ----------------
__global__ __launch_bounds__(256) void k_pool2(const float* __restrict__ sums,
                                               const int* __restrict__ batch,
                                               const float* __restrict__ lw,
                                               const float* __restrict__ lb,
                                               float* __restrict__ out, int Nn) {
  __shared__ float pooled[HC];
  int g = blockIdx.x;
  int t = threadIdx.x;
  int a = 0, b = Nn;
  while (a < b) { int mid = (a + b) >> 1; if (batch[mid] < g) a = mid + 1; else b = mid; }
  int lo = a;
  b = Nn;
  while (a < b) { int mid = (a + b) >> 1; if (batch[mid] < g + 1) a = mid + 1; else b = mid; }
  int hi = a;
  int cnt = hi - lo;
  pooled[t] = sums[g * HC + t] / (float)(cnt > 0 ? cnt : 1);
  __syncthreads();
  if (t < NOUT) {
    float acc = lb[t];
    for (int c = 0; c < HC; ++c) acc += pooled[c] * lw[c * NOUT + t];
    out[g * NOUT + t] = acc;
  }
}

extern "C" void kernel_launch(void* const* d_in, const int* in_sizes, int n_in,
                              void* d_out, int out_size, void* d_ws, size_t ws_size,
                              hipStream_t stream) {
  const float* x_in = (const float*)d_in[0];
  const int* ei     = (const int*)d_in[1];
  const int* batch  = (const int*)d_in[2];
  const float* w1 = (const float*)d_in[3];
  const float* as1 = (const float*)d_in[4];
  const float* ad1 = (const float*)d_in[5];
  const float* b1 = (const float*)d_in[6];
  const float* w2 = (const float*)d_in[7];
  const float* as2 = (const float*)d_in[8];
  const float* ad2 = (const float*)d_in[9];
  const float* b2 = (const float*)d_in[10];
  const float* w3 = (const float*)d_in[11];
  const float* as3 = (const float*)d_in[12];
  const float* ad3 = (const float*)d_in[13];
  const float* b3 = (const float*)d_in[14];
  const float* lw = (const float*)d_in[15];
  const float* lb = (const float*)d_in[16];

  int Nn = in_sizes[2];
  int E = in_sizes[1] / 2;
  const int* esrc = ei;
  const int* edst = ei + E;
  int K1 = in_sizes[0] / Nn;  // 128

  char* ws = (char*)d_ws;
  size_t off = 0;
  auto alloc = [&](size_t bytes) {
    char* p = ws + off;
    off += (bytes + 255) & ~(size_t)255;
    return p;
  };
  ushort* xbuf = (ushort*)alloc((size_t)Nn * HC * 2);   // bf16 layer activations
  ushort* hbuf = (ushort*)alloc((size_t)Nn * HC * 2);   // bf16 h
  ushort* xb0  = (ushort*)alloc((size_t)Nn * K1 * 2);   // bf16 layer-1 input
  ushort* wbuf = (ushort*)alloc((size_t)HC * HC * 2);   // packed W (max K=256)
  float* sbuf = (float*)alloc((size_t)Nn * NH * 4);
  float* dbuf = (float*)alloc((size_t)Nn * NH * 4);
  float* gsum = (float*)alloc((size_t)NGRAPH * HC * 4);
  int* deg  = (int*)alloc((size_t)(Nn + 1) * 4);
  int* ptr  = (int*)alloc((size_t)(Nn + 1) * 4);
  int* cur  = (int*)alloc((size_t)Nn * 4);
  int* csrc = (int*)alloc((size_t)E * 4);

  // CSR by dst
  k_zero_i32<<<(Nn + 255) / 256, 256, 0, stream>>>(deg, Nn);
  k_deg<<<(E + 255) / 256, 256, 0, stream>>>(edst, E, deg);
  k_scan<<<1, 1024, 0, stream>>>(deg, ptr, cur, Nn);
  k_scatter<<<(E + 255) / 256, 256, 0, stream>>>(esrc, edst, E, cur, csrc);

  // layer-1 input to bf16
  k_f2b<<<((Nn * K1 / 4) + 255) / 256, 256, 0, stream>>>(x_in, xb0, Nn * K1);

  const float* Ws[3] = {w1, w2, w3};
  const float* As[3] = {as1, as2, as3};
  const float* Ad[3] = {ad1, ad2, ad3};
  const float* Bs[3] = {b1, b2, b3};

  int gemmGrid = (Nn + 63) / 64;   // 4 waves/block, 16 rows/wave
  int waveGrid = ((Nn * 64) + 255) / 256;
  const ushort* cx = xb0;
  int K = K1;
  for (int l = 0; l < 3; ++l) {
    k_wpack<<<(K * HC + 255) / 256, 256, 0, stream>>>(Ws[l], wbuf, K);
    if (K == 128)
      k_gemm_mfma<128><<<gemmGrid, 256, 0, stream>>>(cx, wbuf, hbuf, Nn);
    else
      k_gemm_mfma<256><<<gemmGrid, 256, 0, stream>>>(cx, wbuf, hbuf, Nn);
    k_sd<<<waveGrid, 256, 0, stream>>>(hbuf, As[l], Ad[l], sbuf, dbuf, Nn);
    k_aggr<<<waveGrid, 256, 0, stream>>>(hbuf, sbuf, dbuf, ptr, csrc, Bs[l], xbuf, Nn);
    cx = xbuf;
    K = HC;
  }
  k_zero_f32<<<(NGRAPH * HC + 255) / 256, 256, 0, stream>>>(gsum, NGRAPH * HC);
  k_pool1<<<(Nn + 63) / 64, 256, 0, stream>>>(xbuf, batch, gsum, Nn);
  k_pool2<<<NGRAPH, 256, 0, stream>>>(gsum, batch, lw, lb, (float*)d_out, Nn);
}

// Round 4
// 511.765 us; speedup vs baseline: 2.4117x; 1.1661x over previous
//
#include <hip/hip_runtime.h>
#include <hip/hip_bf16.h>
#include <math.h>

#define HC 256
#define NH 8
#define NOUT 10
#define NGRAPH 64

typedef __bf16 bf16x8 __attribute__((ext_vector_type(8)));
typedef float f32x4 __attribute__((ext_vector_type(4)));

__device__ __forceinline__ float lrelu(float v) { return v > 0.f ? v : 0.2f * v; }

__device__ __forceinline__ ushort f2bu(float f) {
  __hip_bfloat16 b = __float2bfloat16(f);
  return __builtin_bit_cast(ushort, b);
}
__device__ __forceinline__ float bf2f(ushort u) {
  return __uint_as_float(((unsigned)u) << 16);
}
__device__ __forceinline__ void unp4(uint2 v, float& a, float& b, float& c, float& d) {
  a = __uint_as_float(v.x << 16);
  b = __uint_as_float(v.x & 0xffff0000u);
  c = __uint_as_float(v.y << 16);
  d = __uint_as_float(v.y & 0xffff0000u);
}

// ---------------- CSR build ----------------
__global__ void k_zero_i32(int* p, int n) {
  int i = blockIdx.x * blockDim.x + threadIdx.x;
  if (i < n) p[i] = 0;
}
__global__ void k_zero_f32(float* p, int n) {
  int i = blockIdx.x * blockDim.x + threadIdx.x;
  if (i < n) p[i] = 0.f;
}

__global__ void k_deg(const int* __restrict__ dst, int E, int* __restrict__ deg) {
  int e = blockIdx.x * blockDim.x + threadIdx.x;
  if (e < E) atomicAdd(&deg[dst[e]], 1);
}

// --- parallel scan: 1024 elems/block ---
__global__ __launch_bounds__(256) void k_scan1(const int* __restrict__ deg,
                                               int* __restrict__ bsum, int n) {
  __shared__ int sd[256];
  int t = threadIdx.x;
  int i0 = blockIdx.x * 1024 + t * 4;
  int s = 0;
#pragma unroll
  for (int j = 0; j < 4; ++j) {
    int i = i0 + j;
    if (i < n) s += deg[i];
  }
  sd[t] = s;
  __syncthreads();
  for (int off = 128; off > 0; off >>= 1) {
    if (t < off) sd[t] += sd[t + off];
    __syncthreads();
  }
  if (t == 0) bsum[blockIdx.x] = sd[0];
}

__global__ __launch_bounds__(1024) void k_scan2(const int* __restrict__ bsum,
                                                int* __restrict__ boff,
                                                int* __restrict__ ptr, int B, int n) {
  __shared__ int sd[1024];
  int t = threadIdx.x;
  int v = (t < B) ? bsum[t] : 0;
  sd[t] = v;
  __syncthreads();
  for (int off = 1; off < 1024; off <<= 1) {
    int u = (t >= off) ? sd[t - off] : 0;
    __syncthreads();
    sd[t] += u;
    __syncthreads();
  }
  if (t < B) boff[t] = sd[t] - v;  // exclusive
  if (t == 1023) ptr[n] = sd[1023];
}

__global__ __launch_bounds__(256) void k_scan3(const int* __restrict__ deg,
                                               const int* __restrict__ boff,
                                               int* __restrict__ ptr,
                                               int* __restrict__ cur, int n) {
  __shared__ int sd[256];
  int t = threadIdx.x;
  int i0 = blockIdx.x * 1024 + t * 4;
  int v[4];
#pragma unroll
  for (int j = 0; j < 4; ++j) {
    int i = i0 + j;
    v[j] = (i < n) ? deg[i] : 0;
  }
  int tsum = v[0] + v[1] + v[2] + v[3];
  sd[t] = tsum;
  __syncthreads();
  for (int off = 1; off < 256; off <<= 1) {
    int u = (t >= off) ? sd[t - off] : 0;
    __syncthreads();
    sd[t] += u;
    __syncthreads();
  }
  int base = boff[blockIdx.x] + sd[t] - tsum;
  int run = base;
#pragma unroll
  for (int j = 0; j < 4; ++j) {
    int i = i0 + j;
    if (i < n) { ptr[i] = run; cur[i] = run; }
    run += v[j];
  }
}

__global__ void k_scatter(const int* __restrict__ src, const int* __restrict__ dst, int E,
                          int* __restrict__ cur, int* __restrict__ csrc) {
  int e = blockIdx.x * blockDim.x + threadIdx.x;
  if (e < E) {
    int pos = atomicAdd(&cur[dst[e]], 1);
    csrc[pos] = src[e];
  }
}

// ---------------- W repack to MFMA B-fragment layout, bf16 ----------------
__global__ void k_wpack(const float* __restrict__ w, ushort* __restrict__ wb, int K) {
  int idx = blockIdx.x * blockDim.x + threadIdx.x;
  if (idx >= K * HC) return;
  int i = idx & 7;
  int lane = (idx >> 3) & 63;
  int ct = (idx >> 9) & 15;
  int ks = idx >> 13;
  int k = ks * 32 + (lane >> 4) * 8 + i;
  int col = ct * 16 + (lane & 15);
  wb[idx] = f2bu(w[k * HC + col]);
}

// ---------------- MFMA GEMM + fused attention scores ----------------
// One wave per 16 rows x 256 cols. Epilogue computes s,d via shfl butterfly.
template <int K, bool F32IN>
__global__ __launch_bounds__(256) void k_gemm_sd(const void* __restrict__ xin,
                                                 const ushort* __restrict__ wb,
                                                 ushort* __restrict__ h,
                                                 const float* __restrict__ as,
                                                 const float* __restrict__ ad,
                                                 float* __restrict__ sbuf,
                                                 float* __restrict__ dbuf, int Nn) {
  int wave = (blockIdx.x * blockDim.x + threadIdx.x) >> 6;
  int lane = threadIdx.x & 63;
  int r0 = wave * 16;
  if (r0 >= Nn) return;
  constexpr int NKS = K / 32;
  f32x4 acc[16];
#pragma unroll
  for (int ct = 0; ct < 16; ++ct) acc[ct] = (f32x4){0.f, 0.f, 0.f, 0.f};

  int arow_r = r0 + (lane & 15);
  if (arow_r >= Nn) arow_r = Nn - 1;
  const ushort* arow_b = (const ushort*)xin + (size_t)arow_r * K + (lane >> 4) * 8;
  const float* arow_f = (const float*)xin + (size_t)arow_r * K + (lane >> 4) * 8;
  const ushort* bbase = wb + (size_t)lane * 8;

#pragma unroll
  for (int ks = 0; ks < NKS; ++ks) {
    bf16x8 af;
    if (F32IN) {
      float4 fa = *(const float4*)(arow_f + ks * 32);
      float4 fb = *(const float4*)(arow_f + ks * 32 + 4);
      uint4 packed;
      packed.x = (uint)f2bu(fa.x) | ((uint)f2bu(fa.y) << 16);
      packed.y = (uint)f2bu(fa.z) | ((uint)f2bu(fa.w) << 16);
      packed.z = (uint)f2bu(fb.x) | ((uint)f2bu(fb.y) << 16);
      packed.w = (uint)f2bu(fb.z) | ((uint)f2bu(fb.w) << 16);
      af = __builtin_bit_cast(bf16x8, packed);
    } else {
      uint4 araw = *(const uint4*)(arow_b + ks * 32);
      af = __builtin_bit_cast(bf16x8, araw);
    }
#pragma unroll
    for (int ct = 0; ct < 16; ++ct) {
      uint4 braw = *(const uint4*)(bbase + (size_t)(ks * 16 + ct) * 512);
      bf16x8 bfr = __builtin_bit_cast(bf16x8, braw);
      acc[ct] = __builtin_amdgcn_mfma_f32_16x16x32_bf16(af, bfr, acc[ct], 0, 0, 0);
    }
  }

  // C/D layout: col = ct*16 + colb, row = rq + q
  int colb = lane & 15;
  int rq = r0 + (lane >> 4) * 4;
#pragma unroll
  for (int ct = 0; ct < 16; ++ct) {
#pragma unroll
    for (int q = 0; q < 4; ++q) {
      int row = rq + q;
      if (row < Nn) h[(size_t)row * HC + ct * 16 + colb] = f2bu(acc[ct][q]);
    }
  }

  // fused s,d: s[row][hd] = sum_{col in head} h[row][col]*as_flat[col]
#pragma unroll
  for (int hd = 0; hd < 8; ++hd) {
    float a0 = as[hd * 32 + colb];
    float a1 = as[hd * 32 + 16 + colb];
    float c0 = ad[hd * 32 + colb];
    float c1 = ad[hd * 32 + 16 + colb];
    float sq[4], dq[4];
#pragma unroll
    for (int q = 0; q < 4; ++q) {
      sq[q] = acc[2 * hd][q] * a0 + acc[2 * hd + 1][q] * a1;
      dq[q] = acc[2 * hd][q] * c0 + acc[2 * hd + 1][q] * c1;
    }
#pragma unroll
    for (int msk = 1; msk < 16; msk <<= 1) {
#pragma unroll
      for (int q = 0; q < 4; ++q) {
        sq[q] += __shfl_xor(sq[q], msk, 64);
        dq[q] += __shfl_xor(dq[q], msk, 64);
      }
    }
    if (colb == hd * 2) {
#pragma unroll
      for (int q = 0; q < 4; ++q)
        if (rq + q < Nn) sbuf[(size_t)(rq + q) * NH + hd] = sq[q];
    } else if (colb == hd * 2 + 1) {
#pragma unroll
      for (int q = 0; q < 4; ++q)
        if (rq + q < Nn) dbuf[(size_t)(rq + q) * NH + hd] = dq[q];
    }
  }
}

// ---------------- fused attention aggregation (one wave per dst node) ----------------
// No max-subtraction: softmax is scale-invariant; scores are O(1) here.
__global__ __launch_bounds__(256) void k_aggr(const ushort* __restrict__ h,
                                              const float* __restrict__ s,
                                              const float* __restrict__ dsc,
                                              const int* __restrict__ ptr,
                                              const int* __restrict__ csrc,
                                              const float* __restrict__ bias,
                                              ushort* __restrict__ xout, int Nn) {
  int wid = (blockIdx.x * blockDim.x + threadIdx.x) >> 6;
  int lane = threadIdx.x & 63;
  if (wid >= Nn) return;
  int n = wid;
  int hd = lane >> 3;
  int e0 = ptr[n], e1 = ptr[n + 1];
  float dn = dsc[n * NH + hd];

  float p = __expf(lrelu(s[n * NH + hd] + dn));
  float den0 = p, den1 = 0.f;
  float h0, h1, h2, h3;
  unp4(((const uint2*)(h + (size_t)n * HC))[lane], h0, h1, h2, h3);
  float a0x = p * h0, a0y = p * h1, a0z = p * h2, a0w = p * h3;
  float a1x = 0.f, a1y = 0.f, a1z = 0.f, a1w = 0.f;
  float a2x = 0.f, a2y = 0.f, a2z = 0.f, a2w = 0.f;
  float a3x = 0.f, a3y = 0.f, a3z = 0.f, a3w = 0.f;

  int e = e0;
  for (; e + 8 <= e1; e += 8) {
    int s0 = csrc[e], s1 = csrc[e + 1], s2 = csrc[e + 2], s3 = csrc[e + 3];
    int s4 = csrc[e + 4], s5 = csrc[e + 5], s6 = csrc[e + 6], s7 = csrc[e + 7];
    float x0 = s[s0 * NH + hd], x1 = s[s1 * NH + hd];
    float x2 = s[s2 * NH + hd], x3 = s[s3 * NH + hd];
    float x4 = s[s4 * NH + hd], x5 = s[s5 * NH + hd];
    float x6 = s[s6 * NH + hd], x7 = s[s7 * NH + hd];
    uint2 v0 = ((const uint2*)(h + (size_t)s0 * HC))[lane];
    uint2 v1 = ((const uint2*)(h + (size_t)s1 * HC))[lane];
    uint2 v2 = ((const uint2*)(h + (size_t)s2 * HC))[lane];
    uint2 v3 = ((const uint2*)(h + (size_t)s3 * HC))[lane];
    uint2 v4 = ((const uint2*)(h + (size_t)s4 * HC))[lane];
    uint2 v5 = ((const uint2*)(h + (size_t)s5 * HC))[lane];
    uint2 v6 = ((const uint2*)(h + (size_t)s6 * HC))[lane];
    uint2 v7 = ((const uint2*)(h + (size_t)s7 * HC))[lane];
    float e0x = __expf(lrelu(x0 + dn)), e1x = __expf(lrelu(x1 + dn));
    float e2x = __expf(lrelu(x2 + dn)), e3x = __expf(lrelu(x3 + dn));
    float e4x = __expf(lrelu(x4 + dn)), e5x = __expf(lrelu(x5 + dn));
    float e6x = __expf(lrelu(x6 + dn)), e7x = __expf(lrelu(x7 + dn));
    den0 += (e0x + e1x) + (e2x + e3x);
    den1 += (e4x + e5x) + (e6x + e7x);
    float b0, b1, b2, b3;
    unp4(v0, b0, b1, b2, b3);
    a0x += e0x * b0; a0y += e0x * b1; a0z += e0x * b2; a0w += e0x * b3;
    unp4(v1, b0, b1, b2, b3);
    a1x += e1x * b0; a1y += e1x * b1; a1z += e1x * b2; a1w += e1x * b3;
    unp4(v2, b0, b1, b2, b3);
    a2x += e2x * b0; a2y += e2x * b1; a2z += e2x * b2; a2w += e2x * b3;
    unp4(v3, b0, b1, b2, b3);
    a3x += e3x * b0; a3y += e3x * b1; a3z += e3x * b2; a3w += e3x * b3;
    unp4(v4, b0, b1, b2, b3);
    a0x += e4x * b0; a0y += e4x * b1; a0z += e4x * b2; a0w += e4x * b3;
    unp4(v5, b0, b1, b2, b3);
    a1x += e5x * b0; a1y += e5x * b1; a1z += e5x * b2; a1w += e5x * b3;
    unp4(v6, b0, b1, b2, b3);
    a2x += e6x * b0; a2y += e6x * b1; a2z += e6x * b2; a2w += e6x * b3;
    unp4(v7, b0, b1, b2, b3);
    a3x += e7x * b0; a3y += e7x * b1; a3z += e7x * b2; a3w += e7x * b3;
  }
  for (; e < e1; ++e) {
    int sa = csrc[e];
    float ea = __expf(lrelu(s[sa * NH + hd] + dn));
    den0 += ea;
    uint2 va = ((const uint2*)(h + (size_t)sa * HC))[lane];
    float b0, b1, b2, b3;
    unp4(va, b0, b1, b2, b3);
    a0x += ea * b0; a0y += ea * b1; a0z += ea * b2; a0w += ea * b3;
  }
  float ax = (a0x + a1x) + (a2x + a3x);
  float ay = (a0y + a1y) + (a2y + a3y);
  float az = (a0z + a1z) + (a2z + a3z);
  float aw = (a0w + a1w) + (a2w + a3w);

  float inv = 1.f / ((den0 + den1) + 1e-16f);
  float4 bv = ((const float4*)bias)[lane];
  float ox = ax * inv + bv.x;
  float oy = ay * inv + bv.y;
  float oz = az * inv + bv.z;
  float ow = aw * inv + bv.w;
  ox = ox > 0.f ? ox : __expf(ox) - 1.f;
  oy = oy > 0.f ? oy : __expf(oy) - 1.f;
  oz = oz > 0.f ? oz : __expf(oz) - 1.f;
  ow = ow > 0.f ? ow : __expf(ow) - 1.f;
  uint2 o;
  o.x = (uint)f2bu(ox) | ((uint)f2bu(oy) << 16);
  o.y = (uint)f2bu(oz) | ((uint)f2bu(ow) << 16);
  ((uint2*)(xout + (size_t)n * HC))[lane] = o;
}

// ---------------- mean pool stage 1: segmented partial sums (bf16 in) ----------------
__global__ __launch_bounds__(256) void k_pool1(const ushort* __restrict__ x,
                                               const int* __restrict__ batch,
                                               float* __restrict__ sums, int Nn) {
  __shared__ int bg[64];
  int n0 = blockIdx.x * 64;
  if (n0 >= Nn) return;
  int t = threadIdx.x;
  int n1 = n0 + 64;
  if (n1 > Nn) n1 = Nn;
  if (t < 64 && n0 + t < Nn) bg[t] = batch[n0 + t];
  __syncthreads();
  float acc = 0.f;
  int gcur = bg[0];
  for (int n = n0; n < n1; ++n) {
    int g = bg[n - n0];
    if (g != gcur) {
      atomicAdd(&sums[gcur * HC + t], acc);
      acc = 0.f;
      gcur = g;
    }
    acc += bf2f(x[(size_t)n * HC + t]);
  }
  atomicAdd(&sums[gcur * HC + t], acc);
}

// ---------------- pool finalize: divide by count + linear ----------------
__global__ __launch_bounds__(256) void k_pool2(const float* __restrict__ sums,
                                               const int* __restrict__ batch,
                                               const float* __restrict__ lw,
                                               const float* __restrict__ lb,
                                               float* __restrict__ out, int Nn) {
  __shared__ float pooled[HC];
  int g = blockIdx.x;
  int t = threadIdx.x;
  int a = 0, b = Nn;
  while (a < b) { int mid = (a + b) >> 1; if (batch[mid] < g) a = mid + 1; else b = mid; }
  int lo = a;
  b = Nn;
  while (a < b) { int mid = (a + b) >> 1; if (batch[mid] < g + 1) a = mid + 1; else b = mid; }
  int hi = a;
  int cnt = hi - lo;
  pooled[t] = sums[g * HC + t] / (float)(cnt > 0 ? cnt : 1);
  __syncthreads();
  if (t < NOUT) {
    float acc = lb[t];
    for (int c = 0; c < HC; ++c) acc += pooled[c] * lw[c * NOUT + t];
    out[g * NOUT + t] = acc;
  }
}

extern "C" void kernel_launch(void* const* d_in, const int* in_sizes, int n_in,
                              void* d_out, int out_size, void* d_ws, size_t ws_size,
                              hipStream_t stream) {
  const float* x_in = (const float*)d_in[0];
  const int* ei     = (const int*)d_in[1];
  const int* batch  = (const int*)d_in[2];
  const float* w1 = (const float*)d_in[3];
  const float* as1 = (const float*)d_in[4];
  const float* ad1 = (const float*)d_in[5];
  const float* b1 = (const float*)d_in[6];
  const float* w2 = (const float*)d_in[7];
  const float* as2 = (const float*)d_in[8];
  const float* ad2 = (const float*)d_in[9];
  const float* b2 = (const float*)d_in[10];
  const float* w3 = (const float*)d_in[11];
  const float* as3 = (const float*)d_in[12];
  const float* ad3 = (const float*)d_in[13];
  const float* b3 = (const float*)d_in[14];
  const float* lw = (const float*)d_in[15];
  const float* lb = (const float*)d_in[16];

  int Nn = in_sizes[2];
  int E = in_sizes[1] / 2;
  const int* esrc = ei;
  const int* edst = ei + E;
  int K1 = in_sizes[0] / Nn;  // 128

  char* ws = (char*)d_ws;
  size_t off = 0;
  auto alloc = [&](size_t bytes) {
    char* p = ws + off;
    off += (bytes + 255) & ~(size_t)255;
    return p;
  };
  ushort* xbuf = (ushort*)alloc((size_t)Nn * HC * 2);
  ushort* hbuf = (ushort*)alloc((size_t)Nn * HC * 2);
  ushort* wbuf = (ushort*)alloc((size_t)HC * HC * 2);
  float* sbuf = (float*)alloc((size_t)Nn * NH * 4);
  float* dbuf = (float*)alloc((size_t)Nn * NH * 4);
  float* gsum = (float*)alloc((size_t)NGRAPH * HC * 4);
  int* deg  = (int*)alloc((size_t)(Nn + 1) * 4);
  int* ptr  = (int*)alloc((size_t)(Nn + 1) * 4);
  int* cur  = (int*)alloc((size_t)Nn * 4);
  int* csrc = (int*)alloc((size_t)E * 4);
  int B = (Nn + 1023) / 1024;
  int* bsum = (int*)alloc((size_t)B * 4);
  int* boff = (int*)alloc((size_t)B * 4);

  // CSR by dst (parallel scan)
  k_zero_i32<<<(Nn + 255) / 256, 256, 0, stream>>>(deg, Nn);
  k_deg<<<(E + 255) / 256, 256, 0, stream>>>(edst, E, deg);
  k_scan1<<<B, 256, 0, stream>>>(deg, bsum, Nn);
  k_scan2<<<1, 1024, 0, stream>>>(bsum, boff, ptr, B, Nn);
  k_scan3<<<B, 256, 0, stream>>>(deg, boff, ptr, cur, Nn);
  k_scatter<<<(E + 255) / 256, 256, 0, stream>>>(esrc, edst, E, cur, csrc);

  const float* Ws[3] = {w1, w2, w3};
  const float* As[3] = {as1, as2, as3};
  const float* Ad[3] = {ad1, ad2, ad3};
  const float* Bs[3] = {b1, b2, b3};

  int gemmGrid = (Nn + 63) / 64;   // 4 waves/block, 16 rows/wave
  int waveGrid = ((Nn * 64) + 255) / 256;
  for (int l = 0; l < 3; ++l) {
    k_wpack<<<((l == 0 ? K1 : HC) * HC + 255) / 256, 256, 0, stream>>>(Ws[l], wbuf, l == 0 ? K1 : HC);
    if (l == 0)
      k_gemm_sd<128, true><<<gemmGrid, 256, 0, stream>>>(x_in, wbuf, hbuf, As[l], Ad[l], sbuf, dbuf, Nn);
    else
      k_gemm_sd<256, false><<<gemmGrid, 256, 0, stream>>>(xbuf, wbuf, hbuf, As[l], Ad[l], sbuf, dbuf, Nn);
    k_aggr<<<waveGrid, 256, 0, stream>>>(hbuf, sbuf, dbuf, ptr, csrc, Bs[l], xbuf, Nn);
  }
  k_zero_f32<<<(NGRAPH * HC + 255) / 256, 256, 0, stream>>>(gsum, NGRAPH * HC);
  k_pool1<<<(Nn + 63) / 64, 256, 0, stream>>>(xbuf, batch, gsum, Nn);
  k_pool2<<<NGRAPH, 256, 0, stream>>>(gsum, batch, lw, lb, (float*)d_out, Nn);
}

// Round 5
// 490.856 us; speedup vs baseline: 2.5144x; 1.0426x over previous
//
#include <hip/hip_runtime.h>
#include <hip/hip_bf16.h>
#include <math.h>

#define HC 256
#define NH 8
#define NOUT 10
#define NGRAPH 64

typedef __bf16 bf16x8 __attribute__((ext_vector_type(8)));
typedef float f32x4 __attribute__((ext_vector_type(4)));

__device__ __forceinline__ float lrelu(float v) { return v > 0.f ? v : 0.2f * v; }

__device__ __forceinline__ ushort f2bu(float f) {
  __hip_bfloat16 b = __float2bfloat16(f);
  return __builtin_bit_cast(ushort, b);
}
__device__ __forceinline__ float bf2f(ushort u) {
  return __uint_as_float(((unsigned)u) << 16);
}
__device__ __forceinline__ void unp4(uint2 v, float& a, float& b, float& c, float& d) {
  a = __uint_as_float(v.x << 16);
  b = __uint_as_float(v.x & 0xffff0000u);
  c = __uint_as_float(v.y << 16);
  d = __uint_as_float(v.y & 0xffff0000u);
}

// ---------------- CSR build ----------------
__global__ void k_zero_i32(int* p, int n) {
  int i = blockIdx.x * blockDim.x + threadIdx.x;
  if (i < n) p[i] = 0;
}
__global__ void k_zero_f32(float* p, int n) {
  int i = blockIdx.x * blockDim.x + threadIdx.x;
  if (i < n) p[i] = 0.f;
}

__global__ void k_deg(const int* __restrict__ dst, int E, int* __restrict__ deg) {
  int e = blockIdx.x * blockDim.x + threadIdx.x;
  if (e < E) atomicAdd(&deg[dst[e]], 1);
}

// --- parallel scan: 1024 elems/block ---
__global__ __launch_bounds__(256) void k_scan1(const int* __restrict__ deg,
                                               int* __restrict__ bsum, int n) {
  __shared__ int sd[256];
  int t = threadIdx.x;
  int i0 = blockIdx.x * 1024 + t * 4;
  int s = 0;
#pragma unroll
  for (int j = 0; j < 4; ++j) {
    int i = i0 + j;
    if (i < n) s += deg[i];
  }
  sd[t] = s;
  __syncthreads();
  for (int off = 128; off > 0; off >>= 1) {
    if (t < off) sd[t] += sd[t + off];
    __syncthreads();
  }
  if (t == 0) bsum[blockIdx.x] = sd[0];
}

__global__ __launch_bounds__(1024) void k_scan2(const int* __restrict__ bsum,
                                                int* __restrict__ boff,
                                                int* __restrict__ ptr, int B, int n) {
  __shared__ int sd[1024];
  int t = threadIdx.x;
  int v = (t < B) ? bsum[t] : 0;
  sd[t] = v;
  __syncthreads();
  for (int off = 1; off < 1024; off <<= 1) {
    int u = (t >= off) ? sd[t - off] : 0;
    __syncthreads();
    sd[t] += u;
    __syncthreads();
  }
  if (t < B) boff[t] = sd[t] - v;  // exclusive
  if (t == 1023) ptr[n] = sd[1023];
}

__global__ __launch_bounds__(256) void k_scan3(const int* __restrict__ deg,
                                               const int* __restrict__ boff,
                                               int* __restrict__ ptr,
                                               int* __restrict__ cur, int n) {
  __shared__ int sd[256];
  int t = threadIdx.x;
  int i0 = blockIdx.x * 1024 + t * 4;
  int v[4];
#pragma unroll
  for (int j = 0; j < 4; ++j) {
    int i = i0 + j;
    v[j] = (i < n) ? deg[i] : 0;
  }
  int tsum = v[0] + v[1] + v[2] + v[3];
  sd[t] = tsum;
  __syncthreads();
  for (int off = 1; off < 256; off <<= 1) {
    int u = (t >= off) ? sd[t - off] : 0;
    __syncthreads();
    sd[t] += u;
    __syncthreads();
  }
  int base = boff[blockIdx.x] + sd[t] - tsum;
  int run = base;
#pragma unroll
  for (int j = 0; j < 4; ++j) {
    int i = i0 + j;
    if (i < n) { ptr[i] = run; cur[i] = run; }
    run += v[j];
  }
}

__global__ void k_scatter(const int* __restrict__ src, const int* __restrict__ dst, int E,
                          int* __restrict__ cur, int* __restrict__ csrc) {
  int e = blockIdx.x * blockDim.x + threadIdx.x;
  if (e < E) {
    int pos = atomicAdd(&cur[dst[e]], 1);
    csrc[pos] = src[e];
  }
}

// ---------------- W repack to MFMA B-fragment layout, bf16 ----------------
__global__ void k_wpack(const float* __restrict__ w, ushort* __restrict__ wb, int K) {
  int idx = blockIdx.x * blockDim.x + threadIdx.x;
  if (idx >= K * HC) return;
  int i = idx & 7;
  int lane = (idx >> 3) & 63;
  int ct = (idx >> 9) & 15;
  int ks = idx >> 13;
  int k = ks * 32 + (lane >> 4) * 8 + i;
  int col = ct * 16 + (lane & 15);
  wb[idx] = f2bu(w[k * HC + col]);
}

// ---------------- MFMA GEMM + fused attention scores ----------------
template <int K, bool F32IN>
__global__ __launch_bounds__(256) void k_gemm_sd(const void* __restrict__ xin,
                                                 const ushort* __restrict__ wb,
                                                 ushort* __restrict__ h,
                                                 const float* __restrict__ as,
                                                 const float* __restrict__ ad,
                                                 float* __restrict__ sbuf,
                                                 float* __restrict__ dbuf, int Nn) {
  int wave = (blockIdx.x * blockDim.x + threadIdx.x) >> 6;
  int lane = threadIdx.x & 63;
  int r0 = wave * 16;
  if (r0 >= Nn) return;
  constexpr int NKS = K / 32;
  f32x4 acc[16];
#pragma unroll
  for (int ct = 0; ct < 16; ++ct) acc[ct] = (f32x4){0.f, 0.f, 0.f, 0.f};

  int arow_r = r0 + (lane & 15);
  if (arow_r >= Nn) arow_r = Nn - 1;
  const ushort* arow_b = (const ushort*)xin + (size_t)arow_r * K + (lane >> 4) * 8;
  const float* arow_f = (const float*)xin + (size_t)arow_r * K + (lane >> 4) * 8;
  const ushort* bbase = wb + (size_t)lane * 8;

#pragma unroll
  for (int ks = 0; ks < NKS; ++ks) {
    bf16x8 af;
    if (F32IN) {
      float4 fa = *(const float4*)(arow_f + ks * 32);
      float4 fb = *(const float4*)(arow_f + ks * 32 + 4);
      uint4 packed;
      packed.x = (uint)f2bu(fa.x) | ((uint)f2bu(fa.y) << 16);
      packed.y = (uint)f2bu(fa.z) | ((uint)f2bu(fa.w) << 16);
      packed.z = (uint)f2bu(fb.x) | ((uint)f2bu(fb.y) << 16);
      packed.w = (uint)f2bu(fb.z) | ((uint)f2bu(fb.w) << 16);
      af = __builtin_bit_cast(bf16x8, packed);
    } else {
      uint4 araw = *(const uint4*)(arow_b + ks * 32);
      af = __builtin_bit_cast(bf16x8, araw);
    }
#pragma unroll
    for (int ct = 0; ct < 16; ++ct) {
      uint4 braw = *(const uint4*)(bbase + (size_t)(ks * 16 + ct) * 512);
      bf16x8 bfr = __builtin_bit_cast(bf16x8, braw);
      acc[ct] = __builtin_amdgcn_mfma_f32_16x16x32_bf16(af, bfr, acc[ct], 0, 0, 0);
    }
  }

  int colb = lane & 15;
  int rq = r0 + (lane >> 4) * 4;
#pragma unroll
  for (int ct = 0; ct < 16; ++ct) {
#pragma unroll
    for (int q = 0; q < 4; ++q) {
      int row = rq + q;
      if (row < Nn) h[(size_t)row * HC + ct * 16 + colb] = f2bu(acc[ct][q]);
    }
  }

#pragma unroll
  for (int hd = 0; hd < 8; ++hd) {
    float a0 = as[hd * 32 + colb];
    float a1 = as[hd * 32 + 16 + colb];
    float c0 = ad[hd * 32 + colb];
    float c1 = ad[hd * 32 + 16 + colb];
    float sq[4], dq[4];
#pragma unroll
    for (int q = 0; q < 4; ++q) {
      sq[q] = acc[2 * hd][q] * a0 + acc[2 * hd + 1][q] * a1;
      dq[q] = acc[2 * hd][q] * c0 + acc[2 * hd + 1][q] * c1;
    }
#pragma unroll
    for (int msk = 1; msk < 16; msk <<= 1) {
#pragma unroll
      for (int q = 0; q < 4; ++q) {
        sq[q] += __shfl_xor(sq[q], msk, 64);
        dq[q] += __shfl_xor(dq[q], msk, 64);
      }
    }
    if (colb == hd * 2) {
#pragma unroll
      for (int q = 0; q < 4; ++q)
        if (rq + q < Nn) sbuf[(size_t)(rq + q) * NH + hd] = sq[q];
    } else if (colb == hd * 2 + 1) {
#pragma unroll
      for (int q = 0; q < 4; ++q)
        if (rq + q < Nn) dbuf[(size_t)(rq + q) * NH + hd] = dq[q];
    }
  }
}

// ---------------- fused attention aggregation (one wave per dst node) ----------------
// Score micro-phase: lane = (edge-slot es = lane>>3, head hh = lane&7) computes ONE
// exp(lrelu(s_src + d_dst)) per lane (was 8x redundant). Redistributed via shfl
// (LDS pipe, off the VALU). h-gathers issued before the score chain to overlap.
__global__ __launch_bounds__(256) void k_aggr(const ushort* __restrict__ h,
                                              const float* __restrict__ s,
                                              const float* __restrict__ dsc,
                                              const int* __restrict__ ptr,
                                              const int* __restrict__ csrc,
                                              const float* __restrict__ bias,
                                              ushort* __restrict__ xout, int Nn) {
  int wid = (blockIdx.x * blockDim.x + threadIdx.x) >> 6;
  int lane = threadIdx.x & 63;
  if (wid >= Nn) return;
  int n = wid;
  int hd = lane >> 3;   // head for channel-accumulation layout (lane owns ch 4*lane..4*lane+3)
  int es = lane >> 3;   // edge slot for score layout
  int hh = lane & 7;    // head for score layout
  int e0 = ptr[n], e1 = ptr[n + 1];

  // self score in hh layout
  float d_hh = dsc[n * NH + hh];
  float eself_hh = __expf(lrelu(s[n * NH + hh] + d_hh));

  float den = 0.f;  // per-lane partial: sum of sc over this lane's (es,hh) slots
  float h0, h1, h2, h3;
  unp4(((const uint2*)(h + (size_t)n * HC))[lane], h0, h1, h2, h3);
  float p_hd = __shfl(eself_hh, hd, 64);  // self exp in hd layout
  float a0x = p_hd * h0, a0y = p_hd * h1, a0z = p_hd * h2, a0w = p_hd * h3;
  float a1x = 0.f, a1y = 0.f, a1z = 0.f, a1w = 0.f;
  float a2x = 0.f, a2y = 0.f, a2z = 0.f, a2w = 0.f;
  float a3x = 0.f, a3y = 0.f, a3z = 0.f, a3w = 0.f;

  for (int e8 = e0; e8 < e1; e8 += 8) {
    int r = e1 - e8;
    if (r > 8) r = 8;
    int myE = e8 + es;
    int src_l = (myE < e1) ? csrc[myE] : n;
    // broadcast the 8 src ids; issue h-gathers immediately (overlap score latency)
    int si[8];
#pragma unroll
    for (int i = 0; i < 8; ++i) si[i] = __shfl(src_l, i * 8, 64);
    uint2 v[8];
#pragma unroll
    for (int i = 0; i < 8; ++i)
      if (i < r) v[i] = ((const uint2*)(h + (size_t)si[i] * HC))[lane];
    // one score per lane
    float sv = s[src_l * NH + hh];
    float sc = (myE < e1) ? __expf(lrelu(sv + d_hh)) : 0.f;
    den += sc;
#pragma unroll
    for (int i = 0; i < 8; ++i) {
      if (i < r) {
        float ei = __shfl(sc, i * 8 + hd, 64);
        float b0, b1, b2, b3;
        unp4(v[i], b0, b1, b2, b3);
        if ((i & 3) == 0) { a0x += ei * b0; a0y += ei * b1; a0z += ei * b2; a0w += ei * b3; }
        else if ((i & 3) == 1) { a1x += ei * b0; a1y += ei * b1; a1z += ei * b2; a1w += ei * b3; }
        else if ((i & 3) == 2) { a2x += ei * b0; a2y += ei * b1; a2z += ei * b2; a2w += ei * b3; }
        else { a3x += ei * b0; a3y += ei * b1; a3z += ei * b2; a3w += ei * b3; }
      }
    }
  }
  // reduce den over edge-slot bits (lane bits 3,4,5); result per head hh in every lane
  den += __shfl_xor(den, 8, 64);
  den += __shfl_xor(den, 16, 64);
  den += __shfl_xor(den, 32, 64);
  den += eself_hh;
  // pull denominator for this lane's accumulation head hd (lane 'hd' holds head hh=hd)
  float den_hd = __shfl(den, hd, 64);

  float ax = (a0x + a1x) + (a2x + a3x);
  float ay = (a0y + a1y) + (a2y + a3y);
  float az = (a0z + a1z) + (a2z + a3z);
  float aw = (a0w + a1w) + (a2w + a3w);

  float inv = 1.f / (den_hd + 1e-16f);
  float4 bv = ((const float4*)bias)[lane];
  float ox = ax * inv + bv.x;
  float oy = ay * inv + bv.y;
  float oz = az * inv + bv.z;
  float ow = aw * inv + bv.w;
  ox = ox > 0.f ? ox : __expf(ox) - 1.f;
  oy = oy > 0.f ? oy : __expf(oy) - 1.f;
  oz = oz > 0.f ? oz : __expf(oz) - 1.f;
  ow = ow > 0.f ? ow : __expf(ow) - 1.f;
  uint2 o;
  o.x = (uint)f2bu(ox) | ((uint)f2bu(oy) << 16);
  o.y = (uint)f2bu(oz) | ((uint)f2bu(ow) << 16);
  ((uint2*)(xout + (size_t)n * HC))[lane] = o;
}

// ---------------- mean pool stage 1: segmented partial sums (bf16 in) ----------------
__global__ __launch_bounds__(256) void k_pool1(const ushort* __restrict__ x,
                                               const int* __restrict__ batch,
                                               float* __restrict__ sums, int Nn) {
  __shared__ int bg[64];
  int n0 = blockIdx.x * 64;
  if (n0 >= Nn) return;
  int t = threadIdx.x;
  int n1 = n0 + 64;
  if (n1 > Nn) n1 = Nn;
  if (t < 64 && n0 + t < Nn) bg[t] = batch[n0 + t];
  __syncthreads();
  float acc = 0.f;
  int gcur = bg[0];
  for (int n = n0; n < n1; ++n) {
    int g = bg[n - n0];
    if (g != gcur) {
      atomicAdd(&sums[gcur * HC + t], acc);
      acc = 0.f;
      gcur = g;
    }
    acc += bf2f(x[(size_t)n * HC + t]);
  }
  atomicAdd(&sums[gcur * HC + t], acc);
}

// ---------------- pool finalize: divide by count + linear ----------------
__global__ __launch_bounds__(256) void k_pool2(const float* __restrict__ sums,
                                               const int* __restrict__ batch,
                                               const float* __restrict__ lw,
                                               const float* __restrict__ lb,
                                               float* __restrict__ out, int Nn) {
  __shared__ float pooled[HC];
  int g = blockIdx.x;
  int t = threadIdx.x;
  int a = 0, b = Nn;
  while (a < b) { int mid = (a + b) >> 1; if (batch[mid] < g) a = mid + 1; else b = mid; }
  int lo = a;
  b = Nn;
  while (a < b) { int mid = (a + b) >> 1; if (batch[mid] < g + 1) a = mid + 1; else b = mid; }
  int hi = a;
  int cnt = hi - lo;
  pooled[t] = sums[g * HC + t] / (float)(cnt > 0 ? cnt : 1);
  __syncthreads();
  if (t < NOUT) {
    float acc = lb[t];
    for (int c = 0; c < HC; ++c) acc += pooled[c] * lw[c * NOUT + t];
    out[g * NOUT + t] = acc;
  }
}

extern "C" void kernel_launch(void* const* d_in, const int* in_sizes, int n_in,
                              void* d_out, int out_size, void* d_ws, size_t ws_size,
                              hipStream_t stream) {
  const float* x_in = (const float*)d_in[0];
  const int* ei     = (const int*)d_in[1];
  const int* batch  = (const int*)d_in[2];
  const float* w1 = (const float*)d_in[3];
  const float* as1 = (const float*)d_in[4];
  const float* ad1 = (const float*)d_in[5];
  const float* b1 = (const float*)d_in[6];
  const float* w2 = (const float*)d_in[7];
  const float* as2 = (const float*)d_in[8];
  const float* ad2 = (const float*)d_in[9];
  const float* b2 = (const float*)d_in[10];
  const float* w3 = (const float*)d_in[11];
  const float* as3 = (const float*)d_in[12];
  const float* ad3 = (const float*)d_in[13];
  const float* b3 = (const float*)d_in[14];
  const float* lw = (const float*)d_in[15];
  const float* lb = (const float*)d_in[16];

  int Nn = in_sizes[2];
  int E = in_sizes[1] / 2;
  const int* esrc = ei;
  const int* edst = ei + E;
  int K1 = in_sizes[0] / Nn;  // 128

  char* ws = (char*)d_ws;
  size_t off = 0;
  auto alloc = [&](size_t bytes) {
    char* p = ws + off;
    off += (bytes + 255) & ~(size_t)255;
    return p;
  };
  ushort* xbuf = (ushort*)alloc((size_t)Nn * HC * 2);
  ushort* hbuf = (ushort*)alloc((size_t)Nn * HC * 2);
  ushort* wbuf = (ushort*)alloc((size_t)HC * HC * 2);
  float* sbuf = (float*)alloc((size_t)Nn * NH * 4);
  float* dbuf = (float*)alloc((size_t)Nn * NH * 4);
  float* gsum = (float*)alloc((size_t)NGRAPH * HC * 4);
  int* deg  = (int*)alloc((size_t)(Nn + 1) * 4);
  int* ptr  = (int*)alloc((size_t)(Nn + 1) * 4);
  int* cur  = (int*)alloc((size_t)Nn * 4);
  int* csrc = (int*)alloc((size_t)E * 4);
  int B = (Nn + 1023) / 1024;
  int* bsum = (int*)alloc((size_t)B * 4);
  int* boff = (int*)alloc((size_t)B * 4);

  // CSR by dst (parallel scan)
  k_zero_i32<<<(Nn + 255) / 256, 256, 0, stream>>>(deg, Nn);
  k_deg<<<(E + 255) / 256, 256, 0, stream>>>(edst, E, deg);
  k_scan1<<<B, 256, 0, stream>>>(deg, bsum, Nn);
  k_scan2<<<1, 1024, 0, stream>>>(bsum, boff, ptr, B, Nn);
  k_scan3<<<B, 256, 0, stream>>>(deg, boff, ptr, cur, Nn);
  k_scatter<<<(E + 255) / 256, 256, 0, stream>>>(esrc, edst, E, cur, csrc);

  const float* Ws[3] = {w1, w2, w3};
  const float* As[3] = {as1, as2, as3};
  const float* Ad[3] = {ad1, ad2, ad3};
  const float* Bs[3] = {b1, b2, b3};

  int gemmGrid = (Nn + 63) / 64;
  int waveGrid = ((Nn * 64) + 255) / 256;
  for (int l = 0; l < 3; ++l) {
    k_wpack<<<((l == 0 ? K1 : HC) * HC + 255) / 256, 256, 0, stream>>>(Ws[l], wbuf, l == 0 ? K1 : HC);
    if (l == 0)
      k_gemm_sd<128, true><<<gemmGrid, 256, 0, stream>>>(x_in, wbuf, hbuf, As[l], Ad[l], sbuf, dbuf, Nn);
    else
      k_gemm_sd<256, false><<<gemmGrid, 256, 0, stream>>>(xbuf, wbuf, hbuf, As[l], Ad[l], sbuf, dbuf, Nn);
    k_aggr<<<waveGrid, 256, 0, stream>>>(hbuf, sbuf, dbuf, ptr, csrc, Bs[l], xbuf, Nn);
  }
  k_zero_f32<<<(NGRAPH * HC + 255) / 256, 256, 0, stream>>>(gsum, NGRAPH * HC);
  k_pool1<<<(Nn + 63) / 64, 256, 0, stream>>>(xbuf, batch, gsum, Nn);
  k_pool2<<<NGRAPH, 256, 0, stream>>>(gsum, batch, lw, lb, (float*)d_out, Nn);
}

// Round 6
// 459.677 us; speedup vs baseline: 2.6850x; 1.0678x over previous
//
#include <hip/hip_runtime.h>
#include <hip/hip_bf16.h>
#include <math.h>

#define HC 256
#define NH 8
#define NOUT 10
#define NGRAPH 64

typedef __bf16 bf16x8 __attribute__((ext_vector_type(8)));
typedef float f32x4 __attribute__((ext_vector_type(4)));

__device__ __forceinline__ float lrelu(float v) { return v > 0.f ? v : 0.2f * v; }

__device__ __forceinline__ ushort f2bu(float f) {
  __hip_bfloat16 b = __float2bfloat16(f);
  return __builtin_bit_cast(ushort, b);
}
__device__ __forceinline__ float bf2f(ushort u) {
  return __uint_as_float(((unsigned)u) << 16);
}
__device__ __forceinline__ void unp4(uint2 v, float& a, float& b, float& c, float& d) {
  a = __uint_as_float(v.x << 16);
  b = __uint_as_float(v.x & 0xffff0000u);
  c = __uint_as_float(v.y << 16);
  d = __uint_as_float(v.y & 0xffff0000u);
}

// ---------------- CSR build ----------------
__global__ void k_zero_i32(int* p, int n) {
  int i = blockIdx.x * blockDim.x + threadIdx.x;
  if (i < n) p[i] = 0;
}
__global__ void k_zero_f32(float* p, int n) {
  int i = blockIdx.x * blockDim.x + threadIdx.x;
  if (i < n) p[i] = 0.f;
}

__global__ void k_deg(const int* __restrict__ dst, int E, int* __restrict__ deg) {
  int e = blockIdx.x * blockDim.x + threadIdx.x;
  if (e < E) atomicAdd(&deg[dst[e]], 1);
}

// --- parallel scan: 1024 elems/block ---
__global__ __launch_bounds__(256) void k_scan1(const int* __restrict__ deg,
                                               int* __restrict__ bsum, int n) {
  __shared__ int sd[256];
  int t = threadIdx.x;
  int i0 = blockIdx.x * 1024 + t * 4;
  int s = 0;
#pragma unroll
  for (int j = 0; j < 4; ++j) {
    int i = i0 + j;
    if (i < n) s += deg[i];
  }
  sd[t] = s;
  __syncthreads();
  for (int off = 128; off > 0; off >>= 1) {
    if (t < off) sd[t] += sd[t + off];
    __syncthreads();
  }
  if (t == 0) bsum[blockIdx.x] = sd[0];
}

__global__ __launch_bounds__(1024) void k_scan2(const int* __restrict__ bsum,
                                                int* __restrict__ boff,
                                                int* __restrict__ ptr, int B, int n) {
  __shared__ int sd[1024];
  int t = threadIdx.x;
  int v = (t < B) ? bsum[t] : 0;
  sd[t] = v;
  __syncthreads();
  for (int off = 1; off < 1024; off <<= 1) {
    int u = (t >= off) ? sd[t - off] : 0;
    __syncthreads();
    sd[t] += u;
    __syncthreads();
  }
  if (t < B) boff[t] = sd[t] - v;  // exclusive
  if (t == 1023) ptr[n] = sd[1023];
}

__global__ __launch_bounds__(256) void k_scan3(const int* __restrict__ deg,
                                               const int* __restrict__ boff,
                                               int* __restrict__ ptr,
                                               int* __restrict__ cur, int n) {
  __shared__ int sd[256];
  int t = threadIdx.x;
  int i0 = blockIdx.x * 1024 + t * 4;
  int v[4];
#pragma unroll
  for (int j = 0; j < 4; ++j) {
    int i = i0 + j;
    v[j] = (i < n) ? deg[i] : 0;
  }
  int tsum = v[0] + v[1] + v[2] + v[3];
  sd[t] = tsum;
  __syncthreads();
  for (int off = 1; off < 256; off <<= 1) {
    int u = (t >= off) ? sd[t - off] : 0;
    __syncthreads();
    sd[t] += u;
    __syncthreads();
  }
  int base = boff[blockIdx.x] + sd[t] - tsum;
  int run = base;
#pragma unroll
  for (int j = 0; j < 4; ++j) {
    int i = i0 + j;
    if (i < n) { ptr[i] = run; cur[i] = run; }
    run += v[j];
  }
}

__global__ void k_scatter(const int* __restrict__ src, const int* __restrict__ dst, int E,
                          int* __restrict__ cur, int* __restrict__ csrc) {
  int e = blockIdx.x * blockDim.x + threadIdx.x;
  if (e < E) {
    int pos = atomicAdd(&cur[dst[e]], 1);
    csrc[pos] = src[e];
  }
}

// ---------------- W repack to MFMA B-fragment layout, bf16 ----------------
__global__ void k_wpack(const float* __restrict__ w, ushort* __restrict__ wb, int K) {
  int idx = blockIdx.x * blockDim.x + threadIdx.x;
  if (idx >= K * HC) return;
  int i = idx & 7;
  int lane = (idx >> 3) & 63;
  int ct = (idx >> 9) & 15;
  int ks = idx >> 13;
  int k = ks * 32 + (lane >> 4) * 8 + i;
  int col = ct * 16 + (lane & 15);
  wb[idx] = f2bu(w[k * HC + col]);
}

// ---------------- MFMA GEMM + fused attention scores ----------------
// Block = 4 waves = 64 rows x 256 cols. Wave w owns cols [64w,64w+64) for ALL 64 rows:
// per ks-step 4 A-frags + 4 B-frags feed 16 MFMAs (load:MFMA 8:16, was 17:16).
// A frags identical across the 4 waves (L1-served); B slice reused across blocks (L2).
// Each head's 32 cols sit inside one wave -> exact fused s,d epilogue, no atomics.
template <int K, bool F32IN>
__global__ __launch_bounds__(256) void k_gemm_sd(const void* __restrict__ xin,
                                                 const ushort* __restrict__ wb,
                                                 ushort* __restrict__ h,
                                                 const float* __restrict__ as,
                                                 const float* __restrict__ ad,
                                                 float* __restrict__ sbuf,
                                                 float* __restrict__ dbuf, int Nn) {
  int t = threadIdx.x;
  int wv = t >> 6;          // col group: cols [wv*64, wv*64+64)
  int lane = t & 63;
  int colb = lane & 15;
  int kid = lane >> 4;      // k sub-slot (A) / row quad (C)
  int r0 = blockIdx.x * 64;
  if (r0 >= Nn) return;
  constexpr int NKS = K / 32;

  f32x4 acc[4][4];  // [rt row-subtile][ct local col-tile]
#pragma unroll
  for (int rt = 0; rt < 4; ++rt)
#pragma unroll
    for (int ct = 0; ct < 4; ++ct) acc[rt][ct] = (f32x4){0.f, 0.f, 0.f, 0.f};

  const ushort* arow_b[4];
  const float* arow_f[4];
#pragma unroll
  for (int rt = 0; rt < 4; ++rt) {
    int rr = r0 + rt * 16 + colb;
    if (rr >= Nn) rr = Nn - 1;
    arow_b[rt] = (const ushort*)xin + (size_t)rr * K + kid * 8;
    arow_f[rt] = (const float*)xin + (size_t)rr * K + kid * 8;
  }
  const ushort* bbase = wb + (size_t)(wv * 4) * 512 + (size_t)lane * 8;

#pragma unroll
  for (int ks = 0; ks < NKS; ++ks) {
    bf16x8 af[4];
#pragma unroll
    for (int rt = 0; rt < 4; ++rt) {
      if (F32IN) {
        float4 fa = *(const float4*)(arow_f[rt] + ks * 32);
        float4 fb = *(const float4*)(arow_f[rt] + ks * 32 + 4);
        uint4 packed;
        packed.x = (uint)f2bu(fa.x) | ((uint)f2bu(fa.y) << 16);
        packed.y = (uint)f2bu(fa.z) | ((uint)f2bu(fa.w) << 16);
        packed.z = (uint)f2bu(fb.x) | ((uint)f2bu(fb.y) << 16);
        packed.w = (uint)f2bu(fb.z) | ((uint)f2bu(fb.w) << 16);
        af[rt] = __builtin_bit_cast(bf16x8, packed);
      } else {
        uint4 araw = *(const uint4*)(arow_b[rt] + ks * 32);
        af[rt] = __builtin_bit_cast(bf16x8, araw);
      }
    }
    bf16x8 bf_[4];
#pragma unroll
    for (int ct = 0; ct < 4; ++ct) {
      uint4 braw = *(const uint4*)(bbase + (size_t)(ks * 16 + ct) * 512);
      bf_[ct] = __builtin_bit_cast(bf16x8, braw);
    }
#pragma unroll
    for (int rt = 0; rt < 4; ++rt)
#pragma unroll
      for (int ct = 0; ct < 4; ++ct)
        acc[rt][ct] = __builtin_amdgcn_mfma_f32_16x16x32_bf16(af[rt], bf_[ct], acc[rt][ct], 0, 0, 0);
  }

  // h store: row = r0+rt*16+kid*4+q, col = wv*64+ct*16+colb
#pragma unroll
  for (int rt = 0; rt < 4; ++rt) {
#pragma unroll
    for (int ct = 0; ct < 4; ++ct) {
#pragma unroll
      for (int q = 0; q < 4; ++q) {
        int row = r0 + rt * 16 + kid * 4 + q;
        if (row < Nn) h[(size_t)row * HC + wv * 64 + ct * 16 + colb] = f2bu(acc[rt][ct][q]);
      }
    }
  }

  // fused s,d: heads hp=0,1 -> head = wv*2+hp, ct pair {2hp, 2hp+1}
#pragma unroll
  for (int rt = 0; rt < 4; ++rt) {
#pragma unroll
    for (int hp = 0; hp < 2; ++hp) {
      int head = wv * 2 + hp;
      float a0 = as[head * 32 + colb];
      float a1 = as[head * 32 + 16 + colb];
      float c0 = ad[head * 32 + colb];
      float c1 = ad[head * 32 + 16 + colb];
      float sq[4], dq[4];
#pragma unroll
      for (int q = 0; q < 4; ++q) {
        sq[q] = acc[rt][2 * hp][q] * a0 + acc[rt][2 * hp + 1][q] * a1;
        dq[q] = acc[rt][2 * hp][q] * c0 + acc[rt][2 * hp + 1][q] * c1;
      }
#pragma unroll
      for (int msk = 1; msk < 16; msk <<= 1) {
#pragma unroll
        for (int q = 0; q < 4; ++q) {
          sq[q] += __shfl_xor(sq[q], msk, 64);
          dq[q] += __shfl_xor(dq[q], msk, 64);
        }
      }
      if (colb == 0) {
#pragma unroll
        for (int q = 0; q < 4; ++q) {
          int row = r0 + rt * 16 + kid * 4 + q;
          if (row < Nn) sbuf[(size_t)row * NH + head] = sq[q];
        }
      } else if (colb == 1) {
#pragma unroll
        for (int q = 0; q < 4; ++q) {
          int row = r0 + rt * 16 + kid * 4 + q;
          if (row < Nn) dbuf[(size_t)row * NH + head] = dq[q];
        }
      }
    }
  }
}

// ---------------- fused attention aggregation (one wave per dst node) ----------------
__global__ __launch_bounds__(256) void k_aggr(const ushort* __restrict__ h,
                                              const float* __restrict__ s,
                                              const float* __restrict__ dsc,
                                              const int* __restrict__ ptr,
                                              const int* __restrict__ csrc,
                                              const float* __restrict__ bias,
                                              ushort* __restrict__ xout, int Nn) {
  int wid = (blockIdx.x * blockDim.x + threadIdx.x) >> 6;
  int lane = threadIdx.x & 63;
  if (wid >= Nn) return;
  int n = wid;
  int hd = lane >> 3;
  int es = lane >> 3;
  int hh = lane & 7;
  int e0 = ptr[n], e1 = ptr[n + 1];

  float d_hh = dsc[n * NH + hh];
  float eself_hh = __expf(lrelu(s[n * NH + hh] + d_hh));

  float den = 0.f;
  float h0, h1, h2, h3;
  unp4(((const uint2*)(h + (size_t)n * HC))[lane], h0, h1, h2, h3);
  float p_hd = __shfl(eself_hh, hd, 64);
  float a0x = p_hd * h0, a0y = p_hd * h1, a0z = p_hd * h2, a0w = p_hd * h3;
  float a1x = 0.f, a1y = 0.f, a1z = 0.f, a1w = 0.f;
  float a2x = 0.f, a2y = 0.f, a2z = 0.f, a2w = 0.f;
  float a3x = 0.f, a3y = 0.f, a3z = 0.f, a3w = 0.f;

  for (int e8 = e0; e8 < e1; e8 += 8) {
    int r = e1 - e8;
    if (r > 8) r = 8;
    int myE = e8 + es;
    int src_l = (myE < e1) ? csrc[myE] : n;
    int si[8];
#pragma unroll
    for (int i = 0; i < 8; ++i) si[i] = __shfl(src_l, i * 8, 64);
    uint2 v[8];
#pragma unroll
    for (int i = 0; i < 8; ++i)
      if (i < r) v[i] = ((const uint2*)(h + (size_t)si[i] * HC))[lane];
    float sv = s[src_l * NH + hh];
    float sc = (myE < e1) ? __expf(lrelu(sv + d_hh)) : 0.f;
    den += sc;
#pragma unroll
    for (int i = 0; i < 8; ++i) {
      if (i < r) {
        float ei = __shfl(sc, i * 8 + hd, 64);
        float b0, b1, b2, b3;
        unp4(v[i], b0, b1, b2, b3);
        if ((i & 3) == 0) { a0x += ei * b0; a0y += ei * b1; a0z += ei * b2; a0w += ei * b3; }
        else if ((i & 3) == 1) { a1x += ei * b0; a1y += ei * b1; a1z += ei * b2; a1w += ei * b3; }
        else if ((i & 3) == 2) { a2x += ei * b0; a2y += ei * b1; a2z += ei * b2; a2w += ei * b3; }
        else { a3x += ei * b0; a3y += ei * b1; a3z += ei * b2; a3w += ei * b3; }
      }
    }
  }
  den += __shfl_xor(den, 8, 64);
  den += __shfl_xor(den, 16, 64);
  den += __shfl_xor(den, 32, 64);
  den += eself_hh;
  float den_hd = __shfl(den, hd, 64);

  float ax = (a0x + a1x) + (a2x + a3x);
  float ay = (a0y + a1y) + (a2y + a3y);
  float az = (a0z + a1z) + (a2z + a3z);
  float aw = (a0w + a1w) + (a2w + a3w);

  float inv = 1.f / (den_hd + 1e-16f);
  float4 bv = ((const float4*)bias)[lane];
  float ox = ax * inv + bv.x;
  float oy = ay * inv + bv.y;
  float oz = az * inv + bv.z;
  float ow = aw * inv + bv.w;
  ox = ox > 0.f ? ox : __expf(ox) - 1.f;
  oy = oy > 0.f ? oy : __expf(oy) - 1.f;
  oz = oz > 0.f ? oz : __expf(oz) - 1.f;
  ow = ow > 0.f ? ow : __expf(ow) - 1.f;
  uint2 o;
  o.x = (uint)f2bu(ox) | ((uint)f2bu(oy) << 16);
  o.y = (uint)f2bu(oz) | ((uint)f2bu(ow) << 16);
  ((uint2*)(xout + (size_t)n * HC))[lane] = o;
}

// ---------------- mean pool stage 1: segmented partial sums (bf16 in) ----------------
__global__ __launch_bounds__(256) void k_pool1(const ushort* __restrict__ x,
                                               const int* __restrict__ batch,
                                               float* __restrict__ sums, int Nn) {
  __shared__ int bg[64];
  int n0 = blockIdx.x * 64;
  if (n0 >= Nn) return;
  int t = threadIdx.x;
  int n1 = n0 + 64;
  if (n1 > Nn) n1 = Nn;
  if (t < 64 && n0 + t < Nn) bg[t] = batch[n0 + t];
  __syncthreads();
  float acc = 0.f;
  int gcur = bg[0];
  for (int n = n0; n < n1; ++n) {
    int g = bg[n - n0];
    if (g != gcur) {
      atomicAdd(&sums[gcur * HC + t], acc);
      acc = 0.f;
      gcur = g;
    }
    acc += bf2f(x[(size_t)n * HC + t]);
  }
  atomicAdd(&sums[gcur * HC + t], acc);
}

// ---------------- pool finalize: divide by count + linear ----------------
__global__ __launch_bounds__(256) void k_pool2(const float* __restrict__ sums,
                                               const int* __restrict__ batch,
                                               const float* __restrict__ lw,
                                               const float* __restrict__ lb,
                                               float* __restrict__ out, int Nn) {
  __shared__ float pooled[HC];
  int g = blockIdx.x;
  int t = threadIdx.x;
  int a = 0, b = Nn;
  while (a < b) { int mid = (a + b) >> 1; if (batch[mid] < g) a = mid + 1; else b = mid; }
  int lo = a;
  b = Nn;
  while (a < b) { int mid = (a + b) >> 1; if (batch[mid] < g + 1) a = mid + 1; else b = mid; }
  int hi = a;
  int cnt = hi - lo;
  pooled[t] = sums[g * HC + t] / (float)(cnt > 0 ? cnt : 1);
  __syncthreads();
  if (t < NOUT) {
    float acc = lb[t];
    for (int c = 0; c < HC; ++c) acc += pooled[c] * lw[c * NOUT + t];
    out[g * NOUT + t] = acc;
  }
}

extern "C" void kernel_launch(void* const* d_in, const int* in_sizes, int n_in,
                              void* d_out, int out_size, void* d_ws, size_t ws_size,
                              hipStream_t stream) {
  const float* x_in = (const float*)d_in[0];
  const int* ei     = (const int*)d_in[1];
  const int* batch  = (const int*)d_in[2];
  const float* w1 = (const float*)d_in[3];
  const float* as1 = (const float*)d_in[4];
  const float* ad1 = (const float*)d_in[5];
  const float* b1 = (const float*)d_in[6];
  const float* w2 = (const float*)d_in[7];
  const float* as2 = (const float*)d_in[8];
  const float* ad2 = (const float*)d_in[9];
  const float* b2 = (const float*)d_in[10];
  const float* w3 = (const float*)d_in[11];
  const float* as3 = (const float*)d_in[12];
  const float* ad3 = (const float*)d_in[13];
  const float* b3 = (const float*)d_in[14];
  const float* lw = (const float*)d_in[15];
  const float* lb = (const float*)d_in[16];

  int Nn = in_sizes[2];
  int E = in_sizes[1] / 2;
  const int* esrc = ei;
  const int* edst = ei + E;
  int K1 = in_sizes[0] / Nn;  // 128

  char* ws = (char*)d_ws;
  size_t off = 0;
  auto alloc = [&](size_t bytes) {
    char* p = ws + off;
    off += (bytes + 255) & ~(size_t)255;
    return p;
  };
  ushort* xbuf = (ushort*)alloc((size_t)Nn * HC * 2);
  ushort* hbuf = (ushort*)alloc((size_t)Nn * HC * 2);
  ushort* wbuf = (ushort*)alloc((size_t)HC * HC * 2);
  float* sbuf = (float*)alloc((size_t)Nn * NH * 4);
  float* dbuf = (float*)alloc((size_t)Nn * NH * 4);
  float* gsum = (float*)alloc((size_t)NGRAPH * HC * 4);
  int* deg  = (int*)alloc((size_t)(Nn + 1) * 4);
  int* ptr  = (int*)alloc((size_t)(Nn + 1) * 4);
  int* cur  = (int*)alloc((size_t)Nn * 4);
  int* csrc = (int*)alloc((size_t)E * 4);
  int B = (Nn + 1023) / 1024;
  int* bsum = (int*)alloc((size_t)B * 4);
  int* boff = (int*)alloc((size_t)B * 4);

  // CSR by dst (parallel scan)
  k_zero_i32<<<(Nn + 255) / 256, 256, 0, stream>>>(deg, Nn);
  k_deg<<<(E + 255) / 256, 256, 0, stream>>>(edst, E, deg);
  k_scan1<<<B, 256, 0, stream>>>(deg, bsum, Nn);
  k_scan2<<<1, 1024, 0, stream>>>(bsum, boff, ptr, B, Nn);
  k_scan3<<<B, 256, 0, stream>>>(deg, boff, ptr, cur, Nn);
  k_scatter<<<(E + 255) / 256, 256, 0, stream>>>(esrc, edst, E, cur, csrc);

  const float* Ws[3] = {w1, w2, w3};
  const float* As[3] = {as1, as2, as3};
  const float* Ad[3] = {ad1, ad2, ad3};
  const float* Bs[3] = {b1, b2, b3};

  int gemmGrid = (Nn + 63) / 64;   // 64 rows/block, 4 waves (col groups)
  int waveGrid = ((Nn * 64) + 255) / 256;
  for (int l = 0; l < 3; ++l) {
    k_wpack<<<((l == 0 ? K1 : HC) * HC + 255) / 256, 256, 0, stream>>>(Ws[l], wbuf, l == 0 ? K1 : HC);
    if (l == 0)
      k_gemm_sd<128, true><<<gemmGrid, 256, 0, stream>>>(x_in, wbuf, hbuf, As[l], Ad[l], sbuf, dbuf, Nn);
    else
      k_gemm_sd<256, false><<<gemmGrid, 256, 0, stream>>>(xbuf, wbuf, hbuf, As[l], Ad[l], sbuf, dbuf, Nn);
    k_aggr<<<waveGrid, 256, 0, stream>>>(hbuf, sbuf, dbuf, ptr, csrc, Bs[l], xbuf, Nn);
  }
  k_zero_f32<<<(NGRAPH * HC + 255) / 256, 256, 0, stream>>>(gsum, NGRAPH * HC);
  k_pool1<<<(Nn + 63) / 64, 256, 0, stream>>>(xbuf, batch, gsum, Nn);
  k_pool2<<<NGRAPH, 256, 0, stream>>>(gsum, batch, lw, lb, (float*)d_out, Nn);
}